// Round 6
// baseline (1429.257 us; speedup 1.0000x reference)
//
#include <hip/hip_runtime.h>

typedef __attribute__((ext_vector_type(8))) short bf16x8;
typedef __attribute__((ext_vector_type(4))) float f32x4;
typedef __attribute__((ext_vector_type(16))) float f32x16;

__device__ __forceinline__ float b2f(ushort u) {
    union { unsigned int i; float f; } v; v.i = ((unsigned int)u) << 16; return v.f;
}
__device__ __forceinline__ ushort f2b(float f) {
    union { float f; unsigned int i; } v; v.f = f;
    unsigned int i = v.i;
    return (ushort)((i + 0x7FFFu + ((i >> 16) & 1u)) >> 16);
}
__device__ __forceinline__ void glds16(const ushort* g, ushort* l) {
    __builtin_amdgcn_global_load_lds((const __attribute__((address_space(1))) void*)g,
                                     (__attribute__((address_space(3))) void*)l, 16, 0, 0);
}
// raw barrier with compiler memory fences (no implicit vmcnt/lgkm drain)
__device__ __forceinline__ void BARX() {
    asm volatile("" ::: "memory");
    __builtin_amdgcn_s_barrier();
    asm volatile("" ::: "memory");
}

// ---- LN2: x2(fp32 rows,1024) -> y (bf16) ----
__global__ __launch_bounds__(256) void ln_kernel(const float* __restrict__ x,
                                                 const float* __restrict__ sc,
                                                 const float* __restrict__ bi,
                                                 ushort* __restrict__ y) {
    __shared__ float red[8];
    long row = blockIdx.x;
    const float* xr = x + row * 1024;
    int t = threadIdx.x;
    float4 u = *(const float4*)(xr + t * 4);
    float s = u.x + u.y + u.z + u.w;
    float q = u.x * u.x + u.y * u.y + u.z * u.z + u.w * u.w;
    for (int off = 32; off > 0; off >>= 1) {
        s += __shfl_xor(s, off);
        q += __shfl_xor(q, off);
    }
    if ((t & 63) == 0) { red[t >> 6] = s; red[4 + (t >> 6)] = q; }
    __syncthreads();
    s = red[0] + red[1] + red[2] + red[3];
    q = red[4] + red[5] + red[6] + red[7];
    float mean = s * (1.0f / 1024.0f);
    float var = q * (1.0f / 1024.0f) - mean * mean;
    float rstd = rsqrtf(fmaxf(var, 0.0f) + 1e-6f);
    int c = t * 4;
    float o0 = (u.x - mean) * rstd * sc[c + 0] + bi[c + 0];
    float o1 = (u.y - mean) * rstd * sc[c + 1] + bi[c + 1];
    float o2 = (u.z - mean) * rstd * sc[c + 2] + bi[c + 2];
    float o3 = (u.w - mean) * rstd * sc[c + 3] + bi[c + 3];
    uint2 o;
    o.x = (unsigned int)f2b(o0) | ((unsigned int)f2b(o1) << 16);
    o.y = (unsigned int)f2b(o2) | ((unsigned int)f2b(o3) << 16);
    *(uint2*)(y + row * 1024 + c) = o;
}

// ---- fused LN1 + window partition ----
__global__ __launch_bounds__(256) void ln_part_kernel(const float* __restrict__ x,
                                                      const float* __restrict__ sc,
                                                      const float* __restrict__ bi,
                                                      ushort* __restrict__ wy,
                                                      int win_base, int nvalid) {
    __shared__ float red[8];
    int wt = blockIdx.x;
    int lwin = wt / 196, rr = wt % 196;
    int t = threadIdx.x;
    int valid = 0;
    long xrow = 0;
    if (lwin < nvalid) {
        int gwin = win_base + lwin;
        int img = gwin / 25, wrem = gwin % 25;
        int gh = (wrem / 5) * 14 + rr / 14;
        int gw = (wrem % 5) * 14 + rr % 14;
        if (gh < 64 && gw < 64) {
            valid = 1;
            xrow = (long)img * 4096 + gh * 64 + gw;
        }
    }
    uint2 o; o.x = 0u; o.y = 0u;
    if (valid) {
        const float* xr = x + xrow * 1024;
        float4 u = *(const float4*)(xr + t * 4);
        float s = u.x + u.y + u.z + u.w;
        float q = u.x * u.x + u.y * u.y + u.z * u.z + u.w * u.w;
        for (int off = 32; off > 0; off >>= 1) {
            s += __shfl_xor(s, off);
            q += __shfl_xor(q, off);
        }
        if ((t & 63) == 0) { red[t >> 6] = s; red[4 + (t >> 6)] = q; }
        __syncthreads();
        s = red[0] + red[1] + red[2] + red[3];
        q = red[4] + red[5] + red[6] + red[7];
        float mean = s * (1.0f / 1024.0f);
        float var = q * (1.0f / 1024.0f) - mean * mean;
        float rstd = rsqrtf(fmaxf(var, 0.0f) + 1e-6f);
        int c = t * 4;
        float o0 = (u.x - mean) * rstd * sc[c + 0] + bi[c + 0];
        float o1 = (u.y - mean) * rstd * sc[c + 1] + bi[c + 1];
        float o2 = (u.z - mean) * rstd * sc[c + 2] + bi[c + 2];
        float o3 = (u.w - mean) * rstd * sc[c + 3] + bi[c + 3];
        o.x = (unsigned int)f2b(o0) | ((unsigned int)f2b(o1) << 16);
        o.y = (unsigned int)f2b(o2) | ((unsigned int)f2b(o3) << 16);
    }
    *(uint2*)(wy + (long)wt * 1024 + t * 4) = o;
}

// ---- transpose + cast: in fp32 (K,N) -> out bf16 (N,K) ----
__global__ void transpose_w(const float* __restrict__ in, ushort* __restrict__ out,
                            int K, int N) {
    __shared__ float tile[32][33];
    int n0 = blockIdx.x * 32, k0 = blockIdx.y * 32;
    int tx = threadIdx.x, ty = threadIdx.y;
    for (int i = 0; i < 32; i += 8)
        tile[ty + i][tx] = in[(long)(k0 + ty + i) * N + n0 + tx];
    __syncthreads();
    for (int i = 0; i < 32; i += 8)
        out[(long)(n0 + ty + i) * K + k0 + tx] = f2b(tile[tx][ty + i]);
}

// ---- legacy GEMM (m97 structure, proven) ----
template <int FLAGS, typename OT>
__global__ __launch_bounds__(256) void gemm_bt(const ushort* __restrict__ A,
                                               const ushort* __restrict__ Bt,
                                               const float* __restrict__ bias,
                                               const float* __restrict__ resid,
                                               OT* __restrict__ out,
                                               int M, int N, int K) {
    __shared__ __align__(16) ushort As[128 * 32];
    __shared__ __align__(16) ushort Bs[128 * 32];
    const int tid = threadIdx.x;
    const int lane = tid & 63, w = tid >> 6;
    const int wm = (w >> 1) * 64, wn = (w & 1) * 64;
    const int quad = lane >> 4, l16 = lane & 15;
    const int bm = blockIdx.x * 128, bn = blockIdx.y * 128;
    const int r = tid >> 2, kc = (tid & 3) * 8;
    f32x4 acc[4][4];
#pragma unroll
    for (int i = 0; i < 4; i++)
#pragma unroll
        for (int j = 0; j < 4; j++) acc[i][j] = (f32x4){0.f, 0.f, 0.f, 0.f};
    const ushort* Ag = A + (long)(bm + r) * K + kc;
    const ushort* Bg = Bt + (long)(bn + r) * K + kc;
    ushort* AsW = As + w * 512;
    ushort* BsW = Bs + w * 512;
    for (int k0 = 0; k0 < K; k0 += 32) {
        __syncthreads();
        glds16(Ag + k0, AsW);
        glds16(Ag + (long)64 * K + k0, AsW + 2048);
        glds16(Bg + k0, BsW);
        glds16(Bg + (long)64 * K + k0, BsW + 2048);
        __syncthreads();
        bf16x8 afr[4], bfr[4];
#pragma unroll
        for (int t = 0; t < 4; t++) {
            afr[t] = *(const bf16x8*)&As[(wm + t * 16 + l16) * 32 + quad * 8];
            bfr[t] = *(const bf16x8*)&Bs[(wn + t * 16 + l16) * 32 + quad * 8];
        }
#pragma unroll
        for (int tm = 0; tm < 4; tm++)
#pragma unroll
            for (int tn = 0; tn < 4; tn++)
                acc[tm][tn] = __builtin_amdgcn_mfma_f32_16x16x32_bf16(afr[tm], bfr[tn],
                                                                     acc[tm][tn], 0, 0, 0);
    }
#pragma unroll
    for (int tm = 0; tm < 4; tm++) {
#pragma unroll
        for (int j = 0; j < 4; j++) {
            int gm = bm + wm + tm * 16 + quad * 4 + j;
#pragma unroll
            for (int tn = 0; tn < 4; tn++) {
                int gn = bn + wn + tn * 16 + l16;
                float v = acc[tm][tn][j] + bias[gn];
                if (FLAGS & 1) v = 0.5f * v * (1.0f + erff(v * 0.70710678118654752f));
                if (FLAGS & 2) v += resid[(long)gm * N + gn];
                if (sizeof(OT) == 4) out[(long)gm * N + gn] = (OT)v;
                else out[(long)gm * N + gn] = (OT)f2b(v);
            }
        }
    }
}

// ====== 256x256 GEMM, 32x32x16 engine: A direct global->registers, B via LDS ring-4 ====
// A-fragments are contiguous 16B global loads per lane (no transpose / cross-lane need):
// they bypass LDS entirely (compiler-managed waits; L1 catches the 4-wave duplication,
// per-CU A working set = 16 KB/tile < 32 KB L1).  B keeps the proven counted pipeline:
// 4-deep LDS ring (64 KiB), staged via global_load_lds (2 ops/wave/tile), published
// cross-wave by per-tile asm vmcnt + barrier.  Per tile: 10 VMEM ops (2 B-glds + 8
// A-loads) -> vmcnt(10) retires everything older (order-independent), so at each
// end-of-tile barrier all waves' B-stages two tiles back have landed (r5 invariant).
// Tail peels 3 tiles with counts 8 / 8 / 0.
#define DSR(dst, addr, imm) \
    asm volatile("ds_read_b128 %0, %1 offset:%2" : "=&v"(dst) : "v"(addr), "n"(imm));

#define MFMA32(mf, nf, a, b) \
    acc[mf][nf] = __builtin_amdgcn_mfma_f32_32x32x16_bf16(a, b, acc[mf][nf], 0, 0, 0);

#define RDK0(buf) \
    DSR(y0, b_k0, (buf) * 16384 + 0)    DSR(y1, b_k0, (buf) * 16384 + 2048)
#define RDK1(buf) \
    DSR(Y0, b_k1, (buf) * 16384 + 0)    DSR(Y1, b_k1, (buf) * 16384 + 2048)

#define MFK0(S) \
    MFMA32(0, 0, S##0, y0) MFMA32(0, 1, S##0, y1) MFMA32(1, 0, S##1, y0) MFMA32(1, 1, S##1, y1) \
    MFMA32(2, 0, S##2, y0) MFMA32(2, 1, S##2, y1) MFMA32(3, 0, S##3, y0) MFMA32(3, 1, S##3, y1)
#define MFK1(S) \
    MFMA32(0, 0, S##4, Y0) MFMA32(0, 1, S##4, Y1) MFMA32(1, 0, S##5, Y0) MFMA32(1, 1, S##5, Y1) \
    MFMA32(2, 0, S##6, Y0) MFMA32(2, 1, S##6, Y1) MFMA32(3, 0, S##7, Y0) MFMA32(3, 1, S##7, Y1)

#define LGW2 asm volatile("s_waitcnt lgkmcnt(2)" ::: "memory"); \
    __builtin_amdgcn_sched_barrier(0);
#define LGW0 asm volatile("s_waitcnt lgkmcnt(0)" ::: "memory"); \
    __builtin_amdgcn_sched_barrier(0);

// A-fragment loads for tile ts into named set S (S0..S3 = k0 mf0..3, S4..S7 = k1)
#define ALOAD(S, ts) \
    S##0 = *(const bf16x8*)(Ar0 + (ts) * 32);      \
    S##1 = *(const bf16x8*)(Ar1 + (ts) * 32);      \
    S##2 = *(const bf16x8*)(Ar2 + (ts) * 32);      \
    S##3 = *(const bf16x8*)(Ar3 + (ts) * 32);      \
    S##4 = *(const bf16x8*)(Ar0 + (ts) * 32 + 16); \
    S##5 = *(const bf16x8*)(Ar1 + (ts) * 32 + 16); \
    S##6 = *(const bf16x8*)(Ar2 + (ts) * 32 + 16); \
    S##7 = *(const bf16x8*)(Ar3 + (ts) * 32 + 16);

#define STAGE_B(ts, dbuf) \
    glds16(Bg0 + (long)(ts) * 32, &Bs[dbuf][w * 1024]); \
    glds16(Bg1 + (long)(ts) * 32, &Bs[dbuf][w * 1024 + 512]);

// Full-pipeline K-tile: stage B(ts+3), load A(ts+1) into NXT, compute tile ts from
// CUR + B-buf bb (y-pair primed last tile; Y read here; y-next prefetched mid-tile).
#define TILEX(bb, ts, CUR, NXT) do {                                                     \
    STAGE_B(ts + 3, ((bb) + 3) & 3)                                                      \
    ALOAD(NXT, ts + 1)                                                                   \
    __builtin_amdgcn_sched_barrier(0);                                                   \
    asm volatile("s_waitcnt vmcnt(10)" ::: "memory");                                    \
    RDK1(bb)                                                                             \
    LGW2                                                                                 \
    __builtin_amdgcn_s_setprio(1);                                                       \
    MFK0(CUR)                                                                            \
    __builtin_amdgcn_s_setprio(0);                                                       \
    __builtin_amdgcn_sched_barrier(0);                                                   \
    RDK0(((bb) + 1) & 3)                                                                 \
    LGW2                                                                                 \
    __builtin_amdgcn_s_setprio(1);                                                       \
    MFK1(CUR)                                                                            \
    __builtin_amdgcn_s_setprio(0);                                                       \
    __builtin_amdgcn_sched_barrier(0);                                                   \
    BARX();                                                                              \
} while (0)

template <int FLAGS, typename OT>
__global__ __launch_bounds__(512, 2) void gemm256(const ushort* __restrict__ A,
                                                  const ushort* __restrict__ Bt,
                                                  const float* __restrict__ bias,
                                                  const float* __restrict__ resid,
                                                  OT* __restrict__ out,
                                                  int M, int N, int K, int nbn) {
    __shared__ __align__(64) ushort Bs[4][8192];   // 4 x (256 rows x 32 halfs) = 64 KB
    // bijective XCD swizzle (m204)
    const int nwg = gridDim.x;
    const int orig = blockIdx.x;
    const int q8 = nwg >> 3, r8 = nwg & 7;
    const int xcd = orig & 7, sub = orig >> 3;
    const int wgid = (xcd < r8 ? xcd * (q8 + 1) : r8 * (q8 + 1) + (xcd - r8) * q8) + sub;
    const int bm = (wgid / nbn) * 256, bn = (wgid % nbn) * 256;

    const int tid = threadIdx.x;
    const int lane = tid & 63, w = tid >> 6;
    const int l31 = lane & 31, hi = lane >> 5;
    const int wm = (w >> 2) * 128, wn = (w & 3) * 64;

    // B staging: wave w covers rows w*32..w*32+31 (2 glds x 16 rows); source column
    // chunk pre-swizzled with swz(r)=(r&3)^((r>>2)&1) (rule 21; lane-only expression).
    const int c_st = (((lane & 3) ^ ((lane >> 2) & 3) ^ ((lane >> 4) & 1)) << 3);
    const ushort* Bg0 = Bt + (long)(bn + w * 32 + (lane >> 2)) * K + c_st;
    const ushort* Bg1 = Bg0 + (long)16 * K;

    // A direct-load row pointers: lane's row bm+wm+mf*32+l31, byte base +hi*16
    const ushort* Ar0 = A + (long)(bm + wm + l31) * K + hi * 8;
    const ushort* Ar1 = Ar0 + (long)32 * K;
    const ushort* Ar2 = Ar0 + (long)64 * K;
    const ushort* Ar3 = Ar0 + (long)96 * K;

    // B read addressing (32x32x16 frags): row = wn+nf*32+l31, k-span = hi*8 (+16 k1).
    const int swz = (lane & 3) ^ ((lane >> 2) & 1);
    const int s0 = swz & 1, s1 = swz >> 1;
    const int slot_k0 = (((0 ^ s1) << 1) | (hi ^ s0)) << 4;    // bytes
    const int slot_k1 = (((1 ^ s1) << 1) | (hi ^ s0)) << 4;
    const unsigned Bs0 =
        (unsigned)(size_t)(__attribute__((address_space(3))) ushort*)&Bs[0][0];
    const unsigned b_k0 = Bs0 + (unsigned)((wn + l31) * 64 + slot_k0);
    const unsigned b_k1 = Bs0 + (unsigned)((wn + l31) * 64 + slot_k1);

    f32x16 acc[4][2];
#pragma unroll
    for (int i = 0; i < 4; i++)
#pragma unroll
        for (int j = 0; j < 2; j++)
#pragma unroll
            for (int e = 0; e < 16; e++) acc[i][j][e] = 0.f;

    bf16x8 P0, P1, P2, P3, P4, P5, P6, P7;   // A set (even tiles)
    bf16x8 Q0, Q1, Q2, Q3, Q4, Q5, Q6, Q7;   // A set (odd tiles)
    bf16x8 y0, y1, Y0, Y1;                   // B k0-pair / k1-pair

    // prologue: stage B tiles 0,1,2 (6 glds); load A(0) -> P (8 loads)
    STAGE_B(0, 0)
    STAGE_B(1, 1)
    STAGE_B(2, 2)
    ALOAD(P, 0)
    __builtin_amdgcn_sched_barrier(0);
    asm volatile("s_waitcnt vmcnt(10)" ::: "memory");  // B0,B1 landed (own wave)
    BARX();                                            // published to all waves
    RDK0(0)                                            // prime y with B(0) k0

    const int nt = K >> 5;  // 32 (K=1024) or 128 (K=4096); multiple of 4, >= 8
    for (int t = 0; t + 8 <= nt; t += 4) {
        TILEX(0, t, P, Q);
        TILEX(1, t + 1, Q, P);
        TILEX(2, t + 2, P, Q);
        TILEX(3, t + 3, Q, P);
    }
    // tile nt-4 (bb=0): full; stages B(nt-1) into buf 3
    TILEX(0, nt - 4, P, Q);
    // tile nt-3 (bb=1): no stage; load A(nt-2) -> P; vmcnt(8) retires nt-4's 10 ops
    ALOAD(P, nt - 2)
    __builtin_amdgcn_sched_barrier(0);
    asm volatile("s_waitcnt vmcnt(8)" ::: "memory");
    RDK1(1)
    LGW2
    __builtin_amdgcn_s_setprio(1); MFK0(Q) __builtin_amdgcn_s_setprio(0);
    __builtin_amdgcn_sched_barrier(0);
    RDK0(2)
    LGW2
    __builtin_amdgcn_s_setprio(1); MFK1(Q) __builtin_amdgcn_s_setprio(0);
    __builtin_amdgcn_sched_barrier(0);
    BARX();
    // tile nt-2 (bb=2): no stage; load A(nt-1) -> Q; vmcnt(8)
    ALOAD(Q, nt - 1)
    __builtin_amdgcn_sched_barrier(0);
    asm volatile("s_waitcnt vmcnt(8)" ::: "memory");
    RDK1(2)
    LGW2
    __builtin_amdgcn_s_setprio(1); MFK0(P) __builtin_amdgcn_s_setprio(0);
    __builtin_amdgcn_sched_barrier(0);
    RDK0(3)
    LGW2
    __builtin_amdgcn_s_setprio(1); MFK1(P) __builtin_amdgcn_s_setprio(0);
    __builtin_amdgcn_sched_barrier(0);
    BARX();
    // tile nt-1 (bb=3): final
    asm volatile("s_waitcnt vmcnt(0)" ::: "memory");
    RDK1(3)
    LGW2
    __builtin_amdgcn_s_setprio(1); MFK0(Q) __builtin_amdgcn_s_setprio(0);
    __builtin_amdgcn_sched_barrier(0);
    LGW0
    __builtin_amdgcn_s_setprio(1); MFK1(Q) __builtin_amdgcn_s_setprio(0);
    __builtin_amdgcn_sched_barrier(0);

    // epilogue: C frag layout col=lane&31, row=(reg&3)+8*(reg>>2)+4*hi  [m74/m101]
#pragma unroll
    for (int mf = 0; mf < 4; mf++) {
#pragma unroll
        for (int nf = 0; nf < 2; nf++) {
            const int gn = bn + wn + nf * 32 + l31;
#pragma unroll
            for (int q = 0; q < 4; q++) {
#pragma unroll
                for (int j = 0; j < 4; j++) {
                    const int gm = bm + wm + mf * 32 + q * 8 + j + 4 * hi;
                    const long ro = (long)gm * N;
                    float v = acc[mf][nf][q * 4 + j] + bias[gn];
                    if (FLAGS & 1) v = 0.5f * v * (1.0f + erff(v * 0.70710678118654752f));
                    if (FLAGS & 2) v += resid[ro + gn];
                    if (sizeof(OT) == 4) out[ro + gn] = (OT)v;
                    else out[ro + gn] = (OT)f2b(v);
                }
            }
        }
    }
}

// ---- attention per (window, head): rel-pos via MFMA, 46 KB LDS ----
__global__ __launch_bounds__(256) void attn_kernel(const ushort* __restrict__ qkv,
                                                   ushort* __restrict__ o_out,
                                                   const float* __restrict__ relH,
                                                   const float* __restrict__ relW,
                                                   int win0, long orow0) {
    __shared__ __align__(16) ushort Vt[64 * 200];
    __shared__ __align__(16) ushort Ps[64 * 104];
    __shared__ __align__(16) ushort sc[8 * 448];
    const int head = blockIdx.y;
    const long qbase = (long)blockIdx.x * 196 * 3072 + head * 64;
    const int gwin = win0 + blockIdx.x;
    const int img = gwin / 25, wrem = gwin % 25;
    const int whh = (wrem / 5) * 14, www = (wrem % 5) * 14;
    const int tid = threadIdx.x, lane = tid & 63, w = tid >> 6;
    const int quad = lane >> 4, l16 = lane & 15;

    for (int idx = tid; idx < 196 * 64; idx += 256) {
        int k = idx >> 6, d = idx & 63;
        Vt[d * 200 + k] = qkv[qbase + 2048 + (long)k * 3072 + d];
    }
    __syncthreads();

    bf16x8 bH[2][2], bW[2][2];
#pragma unroll
    for (int nt = 0; nt < 2; nt++) {
        int n = nt * 16 + l16;
#pragma unroll
        for (int kt = 0; kt < 2; kt++) {
            bf16x8 rh = (bf16x8){0, 0, 0, 0, 0, 0, 0, 0};
            bf16x8 rw = (bf16x8){0, 0, 0, 0, 0, 0, 0, 0};
            if (n < 27) {
                const float* ph = relH + n * 64 + kt * 32 + quad * 8;
                const float* pw = relW + n * 64 + kt * 32 + quad * 8;
#pragma unroll
                for (int e = 0; e < 8; e++) {
                    rh[e] = (short)f2b(ph[e]);
                    rw[e] = (short)f2b(pw[e]);
                }
            }
            bH[nt][kt] = rh;
            bW[nt][kt] = rw;
        }
    }

    for (int tr = w; tr < 13; tr += 4) {
        int qrow = tr * 16 + l16;
        if (qrow > 195) qrow = 195;
        bf16x8 qf0 = *(const bf16x8*)(qkv + qbase + (long)qrow * 3072 + quad * 8);
        bf16x8 qf1 = *(const bf16x8*)(qkv + qbase + (long)qrow * 3072 + 32 + quad * 8);

#pragma unroll
        for (int tab = 0; tab < 2; tab++) {
#pragma unroll
            for (int nt = 0; nt < 2; nt++) {
                f32x4 a = (f32x4){0.f, 0.f, 0.f, 0.f};
                a = __builtin_amdgcn_mfma_f32_16x16x32_bf16(qf0, tab ? bW[nt][0] : bH[nt][0],
                                                            a, 0, 0, 0);
                a = __builtin_amdgcn_mfma_f32_16x16x32_bf16(qf1, tab ? bW[nt][1] : bH[nt][1],
                                                            a, 0, 0, 0);
                int col = nt * 16 + l16;
                if (col < 27) {
#pragma unroll
                    for (int j = 0; j < 4; j++)
                        sc[(w * 2 + tab) * 448 + (quad * 4 + j) * 28 + col] = f2b(a[j]);
                }
            }
        }

        f32x4 sf[13];
#pragma unroll
        for (int tc = 0; tc < 13; tc++) {
            int krow = tc * 16 + l16;
            if (krow > 195) krow = 195;
            const ushort* kp = qkv + qbase + 1024 + (long)krow * 3072 + quad * 8;
            bf16x8 kf0 = *(const bf16x8*)kp;
            bf16x8 kf1 = *(const bf16x8*)(kp + 32);
            f32x4 s = (f32x4){0.f, 0.f, 0.f, 0.f};
            s = __builtin_amdgcn_mfma_f32_16x16x32_bf16(qf0, kf0, s, 0, 0, 0);
            s = __builtin_amdgcn_mfma_f32_16x16x32_bf16(qf1, kf1, s, 0, 0, 0);
            sf[tc] = s;
        }
#pragma unroll
        for (int tc = 0; tc < 13; tc++) {
            int c = tc * 16 + l16;
            if (c < 196) {
                int kh = c / 14, kw = c - kh * 14;
#pragma unroll
                for (int j = 0; j < 4; j++) {
                    int rr = tr * 16 + quad * 4 + j;
                    if (rr > 195) rr = 195;
                    float dh = b2f(sc[(w * 2 + 0) * 448 + (quad * 4 + j) * 28 +
                                      (rr / 14 - kh + 13)]);
                    float dw = b2f(sc[(w * 2 + 1) * 448 + (quad * 4 + j) * 28 +
                                      (rr % 14 - kw + 13)]);
                    sf[tc][j] = sf[tc][j] * 0.125f + dh + dw;
                }
            } else {
#pragma unroll
                for (int j = 0; j < 4; j++) sf[tc][j] = -30000.0f;
            }
        }
        f32x4 mx = sf[0];
#pragma unroll
        for (int tc = 1; tc < 13; tc++)
#pragma unroll
            for (int j = 0; j < 4; j++) mx[j] = fmaxf(mx[j], sf[tc][j]);
        for (int off = 1; off < 16; off <<= 1)
#pragma unroll
            for (int j = 0; j < 4; j++) mx[j] = fmaxf(mx[j], __shfl_xor(mx[j], off));
        f32x4 sum = (f32x4){0.f, 0.f, 0.f, 0.f};
#pragma unroll
        for (int tc = 0; tc < 13; tc++)
#pragma unroll
            for (int j = 0; j < 4; j++) {
                float p = __expf(sf[tc][j] - mx[j]);
                sf[tc][j] = p;
                sum[j] += p;
            }
        for (int off = 1; off < 16; off <<= 1)
#pragma unroll
            for (int j = 0; j < 4; j++) sum[j] += __shfl_xor(sum[j], off);
        f32x4 linv;
#pragma unroll
        for (int j = 0; j < 4; j++) linv[j] = 1.0f / sum[j];

        f32x4 oa[4];
#pragma unroll
        for (int tn = 0; tn < 4; tn++) oa[tn] = (f32x4){0.f, 0.f, 0.f, 0.f};
#pragma unroll
        for (int tc = 0; tc < 6; tc++) {
            int c = tc * 16 + l16;
#pragma unroll
            for (int j = 0; j < 4; j++)
                Ps[(w * 16 + quad * 4 + j) * 104 + c] = f2b(sf[tc][j]);
        }
#pragma unroll
        for (int ks = 0; ks < 3; ks++) {
            bf16x8 pf = *(const bf16x8*)&Ps[(w * 16 + l16) * 104 + ks * 32 + quad * 8];
#pragma unroll
            for (int tn = 0; tn < 4; tn++) {
                bf16x8 vf = *(const bf16x8*)&Vt[(tn * 16 + l16) * 200 + ks * 32 + quad * 8];
                oa[tn] = __builtin_amdgcn_mfma_f32_16x16x32_bf16(pf, vf, oa[tn], 0, 0, 0);
            }
        }
#pragma unroll
        for (int tc = 6; tc < 13; tc++) {
            int c = tc * 16 + l16;
            if (c < 196) {
#pragma unroll
                for (int j = 0; j < 4; j++)
                    Ps[(w * 16 + quad * 4 + j) * 104 + (c - 96)] = f2b(sf[tc][j]);
            }
        }
#pragma unroll
        for (int ks = 0; ks < 3; ks++) {
            bf16x8 pf = *(const bf16x8*)&Ps[(w * 16 + l16) * 104 + ks * 32 + quad * 8];
#pragma unroll
            for (int tn = 0; tn < 4; tn++) {
                bf16x8 vf = *(const bf16x8*)&Vt[(tn * 16 + l16) * 200 + 96 + ks * 32 + quad * 8];
                oa[tn] = __builtin_amdgcn_mfma_f32_16x16x32_bf16(pf, vf, oa[tn], 0, 0, 0);
            }
        }
        for (int kk = 192; kk < 196; kk++) {
            float pj[4];
#pragma unroll
            for (int j = 0; j < 4; j++)
                pj[j] = b2f(Ps[(w * 16 + quad * 4 + j) * 104 + 96 + (kk - 192)]);
#pragma unroll
            for (int tn = 0; tn < 4; tn++) {
                float vv = b2f(Vt[(tn * 16 + l16) * 200 + kk]);
#pragma unroll
                for (int j = 0; j < 4; j++) oa[tn][j] += pj[j] * vv;
            }
        }
#pragma unroll
        for (int j = 0; j < 4; j++) {
            int rr = tr * 16 + quad * 4 + j;
            if (rr < 196) {
                int gh = whh + rr / 14, gw = www + rr % 14;
                if (gh < 64 && gw < 64) {
                    long orow = (long)img * 4096 + gh * 64 + gw - orow0;
#pragma unroll
                    for (int tn = 0; tn < 4; tn++)
                        o_out[orow * 1024 + head * 64 + tn * 16 + l16] =
                            f2b(oa[tn][j] * linv[j]);
                }
            }
        }
    }
}

// ---------------- launch ----------------
extern "C" void kernel_launch(void* const* d_in, const int* in_sizes, int n_in,
                              void* d_out, int out_size, void* d_ws, size_t ws_size,
                              hipStream_t stream) {
    const float* x = (const float*)d_in[0];
    const float* n1s = (const float*)d_in[1];
    const float* n1b = (const float*)d_in[2];
    const float* qkvW = (const float*)d_in[3];
    const float* qkvB = (const float*)d_in[4];
    const float* relH = (const float*)d_in[5];
    const float* relW = (const float*)d_in[6];
    const float* projW = (const float*)d_in[7];
    const float* projB = (const float*)d_in[8];
    const float* n2s = (const float*)d_in[9];
    const float* n2b = (const float*)d_in[10];
    const float* fc1W = (const float*)d_in[11];
    const float* fc1B = (const float*)d_in[12];
    const float* fc2W = (const float*)d_in[13];
    const float* fc2B = (const float*)d_in[14];
    float* OUT = (float*)d_out;
    char* ws = (char*)d_ws;

    if (ws_size >= 221000000ULL) {
        // ---- FULL tier (peak 220.2 MB): 11 dispatches, gemm256 pipeline ----
        ushort* T0  = (ushort*)(ws);
        ushort* TP  = (ushort*)(ws + 6291456ULL);
        ushort* TF1 = (ushort*)(ws + 8388608ULL);
        ushort* TF2 = (ushort*)(ws + 16777216ULL);
        ushort* W0  = (ushort*)(ws + 25165824ULL);
        ushort* QKV = (ushort*)(ws + 65536000ULL);
        ushort* AO  = (ushort*)(ws + 186646528ULL);
        ushort* Z   = (ushort*)(ws + 25165824ULL);
        ushort* H   = (ushort*)(ws + 58720256ULL);

        transpose_w<<<dim3(96, 32), dim3(32, 8), 0, stream>>>(qkvW, T0, 1024, 3072);
        transpose_w<<<dim3(32, 32), dim3(32, 8), 0, stream>>>(projW, TP, 1024, 1024);
        transpose_w<<<dim3(128, 32), dim3(32, 8), 0, stream>>>(fc1W, TF1, 1024, 4096);
        transpose_w<<<dim3(32, 128), dim3(32, 8), 0, stream>>>(fc2W, TF2, 4096, 1024);
        ln_part_kernel<<<19712, 256, 0, stream>>>(x, n1s, n1b, W0, 0, 100);
        gemm256<0, ushort><<<924, 512, 0, stream>>>(W0, T0, qkvB, nullptr, QKV,
                                                    19712, 3072, 1024, 12);
        attn_kernel<<<dim3(100, 16), 256, 0, stream>>>(QKV, AO, relH, relW, 0, 0L);
        gemm256<2, float><<<256, 512, 0, stream>>>(AO, TP, projB, x, OUT,
                                                   16384, 1024, 1024, 4);
        ln_kernel<<<16384, 256, 0, stream>>>(OUT, n2s, n2b, Z);
        gemm256<1, ushort><<<1024, 512, 0, stream>>>(Z, TF1, fc1B, nullptr, H,
                                                     16384, 4096, 1024, 16);
        gemm256<2, float><<<256, 512, 0, stream>>>(H, TF2, fc2B, OUT, OUT,
                                                   16384, 1024, 4096, 4);
    } else if (ws_size >= 100000000ULL) {
        // ---- MID tier (peak 99.6 MB): proven round-0 path ----
        ushort* T0  = (ushort*)(ws);
        ushort* TP  = (ushort*)(ws + 6291456ULL);
        ushort* TF1 = (ushort*)(ws + 8388608ULL);
        ushort* TF2 = (ushort*)(ws + 16777216ULL);
        ushort* AO  = (ushort*)(ws + 25165824ULL);
        ushort* W0  = (ushort*)(ws + 58720256ULL);
        ushort* QKV = (ushort*)(ws + 68943872ULL);
        ushort* Z   = (ushort*)(ws + 25165824ULL);
        ushort* H   = (ushort*)(ws + 58720256ULL);

        transpose_w<<<dim3(96, 32), dim3(32, 8), 0, stream>>>(qkvW, T0, 1024, 3072);
        transpose_w<<<dim3(32, 32), dim3(32, 8), 0, stream>>>(projW, TP, 1024, 1024);
        transpose_w<<<dim3(128, 32), dim3(32, 8), 0, stream>>>(fc1W, TF1, 1024, 4096);
        transpose_w<<<dim3(32, 128), dim3(32, 8), 0, stream>>>(fc2W, TF2, 4096, 1024);
        for (int i = 0; i < 4; i++) {
            ln_part_kernel<<<4992, 256, 0, stream>>>(x, n1s, n1b, W0, i * 25, 25);
            gemm_bt<0, ushort><<<dim3(39, 24), 256, 0, stream>>>(W0, T0, qkvB, nullptr,
                                                                 QKV, 4992, 3072, 1024);
            attn_kernel<<<dim3(25, 16), 256, 0, stream>>>(QKV, AO, relH, relW, i * 25, 0L);
        }
        gemm_bt<2, float><<<dim3(128, 8), 256, 0, stream>>>(AO, TP, projB, x, OUT,
                                                            16384, 1024, 1024);
        for (int c = 0; c < 4; c++) {
            float* xc = OUT + (long)c * 4194304;
            ln_kernel<<<4096, 256, 0, stream>>>(xc, n2s, n2b, Z);
            gemm_bt<1, ushort><<<dim3(32, 32), 256, 0, stream>>>(Z, TF1, fc1B, nullptr, H,
                                                                 4096, 4096, 1024);
            gemm_bt<2, float><<<dim3(32, 8), 256, 0, stream>>>(H, TF2, fc2B, xc, xc,
                                                               4096, 1024, 4096);
        }
    } else {
        // ---- FALLBACK (proven 31.2 MB): round-0 path ----
        ushort* T0 = (ushort*)(ws);
        ushort* W0 = (ushort*)(ws + 6291456ULL);
        ushort* W1 = (ushort*)(ws + 16515072ULL);
        ushort* W2 = (ushort*)(ws + 22806528ULL);
        ushort* F1 = (ushort*)(ws);
        ushort* F2 = (ushort*)(ws + 8388608ULL);
        ushort* Z  = (ushort*)(ws + 16777216ULL);
        ushort* H  = (ushort*)(ws + 18874368ULL);

        transpose_w<<<dim3(96, 32), dim3(32, 8), 0, stream>>>(qkvW, T0, 1024, 3072);
        for (int i = 0; i < 4; i++) {
            const float* xi = x + (long)i * 4194304;
            ln_part_kernel<<<4992, 256, 0, stream>>>(x, n1s, n1b, W0, i * 25, 25);
            for (int g = 0; g < 5; g++) {
                gemm_bt<0, ushort><<<dim3(8, 24), 256, 0, stream>>>(
                    W0 + (long)g * 980 * 1024, T0, qkvB, nullptr, W1, 1024, 3072, 1024);
                attn_kernel<<<dim3(5, 16), 256, 0, stream>>>(W1, W2, relH, relW,
                                                             i * 25 + g * 5, (long)i * 4096);
            }
            transpose_w<<<dim3(32, 32), dim3(32, 8), 0, stream>>>(projW, W1, 1024, 1024);
            gemm_bt<2, float><<<dim3(32, 8), 256, 0, stream>>>(
                W2, W1, projB, xi, OUT + (long)i * 4194304, 4096, 1024, 1024);
        }
        transpose_w<<<dim3(128, 32), dim3(32, 8), 0, stream>>>(fc1W, F1, 1024, 4096);
        transpose_w<<<dim3(32, 128), dim3(32, 8), 0, stream>>>(fc2W, F2, 4096, 1024);
        for (int c = 0; c < 16; c++) {
            float* xc = OUT + (long)c * 1048576;
            ln_kernel<<<1024, 256, 0, stream>>>(xc, n2s, n2b, Z);
            gemm_bt<1, ushort><<<dim3(8, 32), 256, 0, stream>>>(Z, F1, fc1B, nullptr, H,
                                                                1024, 4096, 1024);
            gemm_bt<2, float><<<dim3(8, 8), 256, 0, stream>>>(H, F2, fc2B, xc, xc,
                                                              1024, 1024, 4096);
        }
    }
}

// Round 7
// 1052.796 us; speedup vs baseline: 1.3576x; 1.3576x over previous
//
#include <hip/hip_runtime.h>

typedef __attribute__((ext_vector_type(8))) short bf16x8;
typedef __attribute__((ext_vector_type(4))) float f32x4;
typedef __attribute__((ext_vector_type(16))) float f32x16;

__device__ __forceinline__ float b2f(ushort u) {
    union { unsigned int i; float f; } v; v.i = ((unsigned int)u) << 16; return v.f;
}
__device__ __forceinline__ ushort f2b(float f) {
    union { float f; unsigned int i; } v; v.f = f;
    unsigned int i = v.i;
    return (ushort)((i + 0x7FFFu + ((i >> 16) & 1u)) >> 16);
}
__device__ __forceinline__ void glds16(const ushort* g, ushort* l) {
    __builtin_amdgcn_global_load_lds((const __attribute__((address_space(1))) void*)g,
                                     (__attribute__((address_space(3))) void*)l, 16, 0, 0);
}
// raw barrier with compiler memory fences (no implicit vmcnt/lgkm drain)
__device__ __forceinline__ void BARX() {
    asm volatile("" ::: "memory");
    __builtin_amdgcn_s_barrier();
    asm volatile("" ::: "memory");
}

// ---- LN2: x2(fp32 rows,1024) -> y (bf16) ----
__global__ __launch_bounds__(256) void ln_kernel(const float* __restrict__ x,
                                                 const float* __restrict__ sc,
                                                 const float* __restrict__ bi,
                                                 ushort* __restrict__ y) {
    __shared__ float red[8];
    long row = blockIdx.x;
    const float* xr = x + row * 1024;
    int t = threadIdx.x;
    float4 u = *(const float4*)(xr + t * 4);
    float s = u.x + u.y + u.z + u.w;
    float q = u.x * u.x + u.y * u.y + u.z * u.z + u.w * u.w;
    for (int off = 32; off > 0; off >>= 1) {
        s += __shfl_xor(s, off);
        q += __shfl_xor(q, off);
    }
    if ((t & 63) == 0) { red[t >> 6] = s; red[4 + (t >> 6)] = q; }
    __syncthreads();
    s = red[0] + red[1] + red[2] + red[3];
    q = red[4] + red[5] + red[6] + red[7];
    float mean = s * (1.0f / 1024.0f);
    float var = q * (1.0f / 1024.0f) - mean * mean;
    float rstd = rsqrtf(fmaxf(var, 0.0f) + 1e-6f);
    int c = t * 4;
    float o0 = (u.x - mean) * rstd * sc[c + 0] + bi[c + 0];
    float o1 = (u.y - mean) * rstd * sc[c + 1] + bi[c + 1];
    float o2 = (u.z - mean) * rstd * sc[c + 2] + bi[c + 2];
    float o3 = (u.w - mean) * rstd * sc[c + 3] + bi[c + 3];
    uint2 o;
    o.x = (unsigned int)f2b(o0) | ((unsigned int)f2b(o1) << 16);
    o.y = (unsigned int)f2b(o2) | ((unsigned int)f2b(o3) << 16);
    *(uint2*)(y + row * 1024 + c) = o;
}

// ---- fused LN1 + window partition ----
__global__ __launch_bounds__(256) void ln_part_kernel(const float* __restrict__ x,
                                                      const float* __restrict__ sc,
                                                      const float* __restrict__ bi,
                                                      ushort* __restrict__ wy,
                                                      int win_base, int nvalid) {
    __shared__ float red[8];
    int wt = blockIdx.x;
    int lwin = wt / 196, rr = wt % 196;
    int t = threadIdx.x;
    int valid = 0;
    long xrow = 0;
    if (lwin < nvalid) {
        int gwin = win_base + lwin;
        int img = gwin / 25, wrem = gwin % 25;
        int gh = (wrem / 5) * 14 + rr / 14;
        int gw = (wrem % 5) * 14 + rr % 14;
        if (gh < 64 && gw < 64) {
            valid = 1;
            xrow = (long)img * 4096 + gh * 64 + gw;
        }
    }
    uint2 o; o.x = 0u; o.y = 0u;
    if (valid) {
        const float* xr = x + xrow * 1024;
        float4 u = *(const float4*)(xr + t * 4);
        float s = u.x + u.y + u.z + u.w;
        float q = u.x * u.x + u.y * u.y + u.z * u.z + u.w * u.w;
        for (int off = 32; off > 0; off >>= 1) {
            s += __shfl_xor(s, off);
            q += __shfl_xor(q, off);
        }
        if ((t & 63) == 0) { red[t >> 6] = s; red[4 + (t >> 6)] = q; }
        __syncthreads();
        s = red[0] + red[1] + red[2] + red[3];
        q = red[4] + red[5] + red[6] + red[7];
        float mean = s * (1.0f / 1024.0f);
        float var = q * (1.0f / 1024.0f) - mean * mean;
        float rstd = rsqrtf(fmaxf(var, 0.0f) + 1e-6f);
        int c = t * 4;
        float o0 = (u.x - mean) * rstd * sc[c + 0] + bi[c + 0];
        float o1 = (u.y - mean) * rstd * sc[c + 1] + bi[c + 1];
        float o2 = (u.z - mean) * rstd * sc[c + 2] + bi[c + 2];
        float o3 = (u.w - mean) * rstd * sc[c + 3] + bi[c + 3];
        o.x = (unsigned int)f2b(o0) | ((unsigned int)f2b(o1) << 16);
        o.y = (unsigned int)f2b(o2) | ((unsigned int)f2b(o3) << 16);
    }
    *(uint2*)(wy + (long)wt * 1024 + t * 4) = o;
}

// ---- transpose + cast: in fp32 (K,N) -> out bf16 (N,K) ----
__global__ void transpose_w(const float* __restrict__ in, ushort* __restrict__ out,
                            int K, int N) {
    __shared__ float tile[32][33];
    int n0 = blockIdx.x * 32, k0 = blockIdx.y * 32;
    int tx = threadIdx.x, ty = threadIdx.y;
    for (int i = 0; i < 32; i += 8)
        tile[ty + i][tx] = in[(long)(k0 + ty + i) * N + n0 + tx];
    __syncthreads();
    for (int i = 0; i < 32; i += 8)
        out[(long)(n0 + ty + i) * K + k0 + tx] = f2b(tile[tx][ty + i]);
}

// ---- legacy GEMM (m97 structure, proven) ----
template <int FLAGS, typename OT>
__global__ __launch_bounds__(256) void gemm_bt(const ushort* __restrict__ A,
                                               const ushort* __restrict__ Bt,
                                               const float* __restrict__ bias,
                                               const float* __restrict__ resid,
                                               OT* __restrict__ out,
                                               int M, int N, int K) {
    __shared__ __align__(16) ushort As[128 * 32];
    __shared__ __align__(16) ushort Bs[128 * 32];
    const int tid = threadIdx.x;
    const int lane = tid & 63, w = tid >> 6;
    const int wm = (w >> 1) * 64, wn = (w & 1) * 64;
    const int quad = lane >> 4, l16 = lane & 15;
    const int bm = blockIdx.x * 128, bn = blockIdx.y * 128;
    const int r = tid >> 2, kc = (tid & 3) * 8;
    f32x4 acc[4][4];
#pragma unroll
    for (int i = 0; i < 4; i++)
#pragma unroll
        for (int j = 0; j < 4; j++) acc[i][j] = (f32x4){0.f, 0.f, 0.f, 0.f};
    const ushort* Ag = A + (long)(bm + r) * K + kc;
    const ushort* Bg = Bt + (long)(bn + r) * K + kc;
    ushort* AsW = As + w * 512;
    ushort* BsW = Bs + w * 512;
    for (int k0 = 0; k0 < K; k0 += 32) {
        __syncthreads();
        glds16(Ag + k0, AsW);
        glds16(Ag + (long)64 * K + k0, AsW + 2048);
        glds16(Bg + k0, BsW);
        glds16(Bg + (long)64 * K + k0, BsW + 2048);
        __syncthreads();
        bf16x8 afr[4], bfr[4];
#pragma unroll
        for (int t = 0; t < 4; t++) {
            afr[t] = *(const bf16x8*)&As[(wm + t * 16 + l16) * 32 + quad * 8];
            bfr[t] = *(const bf16x8*)&Bs[(wn + t * 16 + l16) * 32 + quad * 8];
        }
#pragma unroll
        for (int tm = 0; tm < 4; tm++)
#pragma unroll
            for (int tn = 0; tn < 4; tn++)
                acc[tm][tn] = __builtin_amdgcn_mfma_f32_16x16x32_bf16(afr[tm], bfr[tn],
                                                                     acc[tm][tn], 0, 0, 0);
    }
#pragma unroll
    for (int tm = 0; tm < 4; tm++) {
#pragma unroll
        for (int j = 0; j < 4; j++) {
            int gm = bm + wm + tm * 16 + quad * 4 + j;
#pragma unroll
            for (int tn = 0; tn < 4; tn++) {
                int gn = bn + wn + tn * 16 + l16;
                float v = acc[tm][tn][j] + bias[gn];
                if (FLAGS & 1) v = 0.5f * v * (1.0f + erff(v * 0.70710678118654752f));
                if (FLAGS & 2) v += resid[(long)gm * N + gn];
                if (sizeof(OT) == 4) out[(long)gm * N + gn] = (OT)v;
                else out[(long)gm * N + gn] = (OT)f2b(v);
            }
        }
    }
}

// ======== 256x256 GEMM: 8-phase-style convoy (T3+T4), 32x32x16 engine, BK=64 ========
// 512 threads, 8 waves (2Mx4N); per-wave C 128x64 = 4 mf x 2 nf frags of 32x32.
// LDS 128 KiB: A[2 slots][2 halves][128][64] + B same (B at +32768 halfs); slot = s&1.
// Per K-step s (64 wide): 4 phases, each {ds_reads, stage 1 half-tile of step s+1
// (2 glds), barrier, lgkmcnt(0), setprio, 8 MFMA, setprio}; vmcnt(0)+barrier once
// at P3 (stages have 1-4 phases of lead). Publication: body(s) reads slot s&1
// staged in body(s-1), published by its final barrier; body(s)'s writes to slot
// s^1 come after body(s-1)'s last reads (same barrier) -> no WAR.
// T2 swizzle: phys_slot = slot ^ (row&7)  (16B slots, 128B rows) on BOTH the
// pre-swizzled global staging source and the ds_read addresses (rule 21).
#define DSR(dst, addr, imm) \
    asm volatile("ds_read_b128 %0, %1 offset:%2" : "=&v"(dst) : "v"(addr), "n"(imm));

#define MFMA32(mf, nf, a, b) \
    acc[mf][nf] = __builtin_amdgcn_mfma_f32_32x32x16_bf16(a, b, acc[mf][nf], 0, 0, 0);

#define LGKM0 asm volatile("s_waitcnt lgkmcnt(0)" ::: "memory"); \
    __builtin_amdgcn_sched_barrier(0);
#define VMCNT0 asm volatile("s_waitcnt vmcnt(0)" ::: "memory");
#define SBAR __builtin_amdgcn_sched_barrier(0);

#define RDA(c, q) \
    DSR(aa0, adA0, (c) * 32768 + (2 * (q) + 0) * 4096) \
    DSR(aa1, adA1, (c) * 32768 + (2 * (q) + 0) * 4096) \
    DSR(aa2, adA2, (c) * 32768 + (2 * (q) + 0) * 4096) \
    DSR(aa3, adA3, (c) * 32768 + (2 * (q) + 0) * 4096) \
    DSR(ab0, adA0, (c) * 32768 + (2 * (q) + 1) * 4096) \
    DSR(ab1, adA1, (c) * 32768 + (2 * (q) + 1) * 4096) \
    DSR(ab2, adA2, (c) * 32768 + (2 * (q) + 1) * 4096) \
    DSR(ab3, adA3, (c) * 32768 + (2 * (q) + 1) * 4096)

#define RDB(c, r) \
    DSR(bb0, adB0, (c) * 32768 + (r) * 4096) \
    DSR(bb1, adB1, (c) * 32768 + (r) * 4096) \
    DSR(bb2, adB2, (c) * 32768 + (r) * 4096) \
    DSR(bb3, adB3, (c) * 32768 + (r) * 4096)

#define MFP(q, r) \
    MFMA32(2 * (q) + 0, r, aa0, bb0) MFMA32(2 * (q) + 1, r, ab0, bb0) \
    MFMA32(2 * (q) + 0, r, aa1, bb1) MFMA32(2 * (q) + 1, r, ab1, bb1) \
    MFMA32(2 * (q) + 0, r, aa2, bb2) MFMA32(2 * (q) + 1, r, ab2, bb2) \
    MFMA32(2 * (q) + 0, r, aa3, bb3) MFMA32(2 * (q) + 1, r, ab3, bb3)

#define STA(cn, h, ss) \
    glds16(AgS + (long)((h) * 128 + 0) * K + (long)(ss) * 64, \
           LDS + (cn) * 16384 + (h) * 8192 + (w * 16 + 0) * 64); \
    glds16(AgS + (long)((h) * 128 + 8) * K + (long)(ss) * 64, \
           LDS + (cn) * 16384 + (h) * 8192 + (w * 16 + 8) * 64); \
    SBAR
#define STB(cn, h, ss) \
    glds16(BgS + (long)((h) * 128 + 0) * K + (long)(ss) * 64, \
           LDS + 32768 + (cn) * 16384 + (h) * 8192 + (w * 16 + 0) * 64); \
    glds16(BgS + (long)((h) * 128 + 8) * K + (long)(ss) * 64, \
           LDS + 32768 + (cn) * 16384 + (h) * 8192 + (w * 16 + 8) * 64); \
    SBAR

#define BODY(c, s, STG) do {                                          \
    RDA(c, 0) RDB(c, 0)                                               \
    if (STG) { STA((c) ^ 1, 0, (s) + 1) }                             \
    BARX(); LGKM0;                                                    \
    __builtin_amdgcn_s_setprio(1); MFP(0, 0)                          \
    __builtin_amdgcn_s_setprio(0); SBAR                               \
    RDB(c, 1)                                                         \
    if (STG) { STA((c) ^ 1, 1, (s) + 1) }                             \
    BARX(); LGKM0;                                                    \
    __builtin_amdgcn_s_setprio(1); MFP(0, 1)                          \
    __builtin_amdgcn_s_setprio(0); SBAR                               \
    RDA(c, 1) RDB(c, 0)                                               \
    if (STG) { STB((c) ^ 1, 0, (s) + 1) }                             \
    BARX(); LGKM0;                                                    \
    __builtin_amdgcn_s_setprio(1); MFP(1, 0)                          \
    __builtin_amdgcn_s_setprio(0); SBAR                               \
    RDB(c, 1)                                                         \
    if (STG) { STB((c) ^ 1, 1, (s) + 1) }                             \
    BARX(); LGKM0;                                                    \
    __builtin_amdgcn_s_setprio(1); MFP(1, 1)                          \
    __builtin_amdgcn_s_setprio(0); SBAR                               \
    if (STG) { VMCNT0; BARX(); }                                      \
} while (0)

template <int FLAGS, typename OT>
__global__ __launch_bounds__(512, 2) void gemm256(const ushort* __restrict__ A,
                                                  const ushort* __restrict__ Bt,
                                                  const float* __restrict__ bias,
                                                  const float* __restrict__ resid,
                                                  OT* __restrict__ out,
                                                  int M, int N, int K, int nbn) {
    __shared__ __align__(64) ushort LDS[65536];   // A 64KB @0, B 64KB @32768 halfs
    // bijective XCD swizzle (m204)
    const int nwg = gridDim.x;
    const int orig = blockIdx.x;
    const int q8 = nwg >> 3, r8 = nwg & 7;
    const int xcd = orig & 7, sub = orig >> 3;
    const int wgid = (xcd < r8 ? xcd * (q8 + 1) : r8 * (q8 + 1) + (xcd - r8) * q8) + sub;
    const int bm = (wgid / nbn) * 256, bn = (wgid % nbn) * 256;

    const int tid = threadIdx.x;
    const int lane = tid & 63, w = tid >> 6;
    const int l31 = lane & 31, hi = lane >> 5;
    const int wm = (w >> 2) * 128, wn = (w & 3) * 64;
    const int H = w >> 2;                 // A half this wave reads
    const int hB = (w >> 1) & 1;          // B half this wave reads
    const int bsub = (w & 1) * 8192;      // (wn&64) rows in bytes

    // ---- staging source pointers (pre-swizzled: src chunk = (l&7) ^ (row&7)) ----
    const int ly = lane >> 3, lx = lane & 7;
    const int schunk = (lx ^ ly) * 8;     // halfs
    const ushort* AgS = A + (long)(bm + w * 16 + ly) * K + schunk;
    const ushort* BgS = Bt + (long)(bn + w * 16 + ly) * K + schunk;

    // ---- ds_read addresses: row part l31*128, slot part ((k*2+hi)^(l31&7))<<4 ----
    const unsigned As0B =
        (unsigned)(size_t)(__attribute__((address_space(3))) ushort*)&LDS[0];
    const int e3 = l31 & 7;
#define LPX(k) ((unsigned)(l31 * 128 + ((((k) * 2 + hi) ^ e3) << 4)))
    const unsigned adA0 = As0B + H * 16384 + LPX(0);
    const unsigned adA1 = As0B + H * 16384 + LPX(1);
    const unsigned adA2 = As0B + H * 16384 + LPX(2);
    const unsigned adA3 = As0B + H * 16384 + LPX(3);
    const unsigned adB0 = As0B + 65536 + hB * 16384 + bsub + LPX(0);
    const unsigned adB1 = As0B + 65536 + hB * 16384 + bsub + LPX(1);
    const unsigned adB2 = As0B + 65536 + hB * 16384 + bsub + LPX(2);
    const unsigned adB3 = As0B + 65536 + hB * 16384 + bsub + LPX(3);
#undef LPX

    f32x16 acc[4][2];
#pragma unroll
    for (int i = 0; i < 4; i++)
#pragma unroll
        for (int j = 0; j < 2; j++)
#pragma unroll
            for (int e = 0; e < 16; e++) acc[i][j][e] = 0.f;

    bf16x8 aa0, aa1, aa2, aa3, ab0, ab1, ab2, ab3;   // A frags (mf pair) x k16
    bf16x8 bb0, bb1, bb2, bb3;                        // B frags (one nf) x k16

    // prologue: stage step 0 -> slot 0 (8 glds), publish
    STA(0, 0, 0) STA(0, 1, 0) STB(0, 0, 0) STB(0, 1, 0)
    VMCNT0; BARX();

    const int nt = K >> 6;  // 16 (K=1024) or 64 (K=4096); even, >= 4
    for (int s2 = 0; s2 + 2 < nt; s2 += 2) {
        BODY(0, s2, 1);
        BODY(1, s2 + 1, 1);
    }
    BODY(0, nt - 2, 1);   // stages step nt-1 -> slot 1
    BODY(1, nt - 1, 0);   // final, no staging

    // epilogue: C frag layout col=lane&31, row=(reg&3)+8*(reg>>2)+4*hi  [m74/m101]
#pragma unroll
    for (int mf = 0; mf < 4; mf++) {
#pragma unroll
        for (int nf = 0; nf < 2; nf++) {
            const int gn = bn + wn + nf * 32 + l31;
#pragma unroll
            for (int q = 0; q < 4; q++) {
#pragma unroll
                for (int j = 0; j < 4; j++) {
                    const int gm = bm + wm + mf * 32 + q * 8 + j + 4 * hi;
                    const long ro = (long)gm * N;
                    float v = acc[mf][nf][q * 4 + j] + bias[gn];
                    if (FLAGS & 1) v = 0.5f * v * (1.0f + erff(v * 0.70710678118654752f));
                    if (FLAGS & 2) v += resid[ro + gn];
                    if (sizeof(OT) == 4) out[ro + gn] = (OT)v;
                    else out[ro + gn] = (OT)f2b(v);
                }
            }
        }
    }
}

// ---- attention per (window, head): rel-pos via MFMA, 46 KB LDS ----
__global__ __launch_bounds__(256) void attn_kernel(const ushort* __restrict__ qkv,
                                                   ushort* __restrict__ o_out,
                                                   const float* __restrict__ relH,
                                                   const float* __restrict__ relW,
                                                   int win0, long orow0) {
    __shared__ __align__(16) ushort Vt[64 * 200];
    __shared__ __align__(16) ushort Ps[64 * 104];
    __shared__ __align__(16) ushort sc[8 * 448];
    const int head = blockIdx.y;
    const long qbase = (long)blockIdx.x * 196 * 3072 + head * 64;
    const int gwin = win0 + blockIdx.x;
    const int img = gwin / 25, wrem = gwin % 25;
    const int whh = (wrem / 5) * 14, www = (wrem % 5) * 14;
    const int tid = threadIdx.x, lane = tid & 63, w = tid >> 6;
    const int quad = lane >> 4, l16 = lane & 15;

    for (int idx = tid; idx < 196 * 64; idx += 256) {
        int k = idx >> 6, d = idx & 63;
        Vt[d * 200 + k] = qkv[qbase + 2048 + (long)k * 3072 + d];
    }
    __syncthreads();

    bf16x8 bH[2][2], bW[2][2];
#pragma unroll
    for (int nt = 0; nt < 2; nt++) {
        int n = nt * 16 + l16;
#pragma unroll
        for (int kt = 0; kt < 2; kt++) {
            bf16x8 rh = (bf16x8){0, 0, 0, 0, 0, 0, 0, 0};
            bf16x8 rw = (bf16x8){0, 0, 0, 0, 0, 0, 0, 0};
            if (n < 27) {
                const float* ph = relH + n * 64 + kt * 32 + quad * 8;
                const float* pw = relW + n * 64 + kt * 32 + quad * 8;
#pragma unroll
                for (int e = 0; e < 8; e++) {
                    rh[e] = (short)f2b(ph[e]);
                    rw[e] = (short)f2b(pw[e]);
                }
            }
            bH[nt][kt] = rh;
            bW[nt][kt] = rw;
        }
    }

    for (int tr = w; tr < 13; tr += 4) {
        int qrow = tr * 16 + l16;
        if (qrow > 195) qrow = 195;
        bf16x8 qf0 = *(const bf16x8*)(qkv + qbase + (long)qrow * 3072 + quad * 8);
        bf16x8 qf1 = *(const bf16x8*)(qkv + qbase + (long)qrow * 3072 + 32 + quad * 8);

#pragma unroll
        for (int tab = 0; tab < 2; tab++) {
#pragma unroll
            for (int nt = 0; nt < 2; nt++) {
                f32x4 a = (f32x4){0.f, 0.f, 0.f, 0.f};
                a = __builtin_amdgcn_mfma_f32_16x16x32_bf16(qf0, tab ? bW[nt][0] : bH[nt][0],
                                                            a, 0, 0, 0);
                a = __builtin_amdgcn_mfma_f32_16x16x32_bf16(qf1, tab ? bW[nt][1] : bH[nt][1],
                                                            a, 0, 0, 0);
                int col = nt * 16 + l16;
                if (col < 27) {
#pragma unroll
                    for (int j = 0; j < 4; j++)
                        sc[(w * 2 + tab) * 448 + (quad * 4 + j) * 28 + col] = f2b(a[j]);
                }
            }
        }

        f32x4 sf[13];
#pragma unroll
        for (int tc = 0; tc < 13; tc++) {
            int krow = tc * 16 + l16;
            if (krow > 195) krow = 195;
            const ushort* kp = qkv + qbase + 1024 + (long)krow * 3072 + quad * 8;
            bf16x8 kf0 = *(const bf16x8*)kp;
            bf16x8 kf1 = *(const bf16x8*)(kp + 32);
            f32x4 s = (f32x4){0.f, 0.f, 0.f, 0.f};
            s = __builtin_amdgcn_mfma_f32_16x16x32_bf16(qf0, kf0, s, 0, 0, 0);
            s = __builtin_amdgcn_mfma_f32_16x16x32_bf16(qf1, kf1, s, 0, 0, 0);
            sf[tc] = s;
        }
#pragma unroll
        for (int tc = 0; tc < 13; tc++) {
            int c = tc * 16 + l16;
            if (c < 196) {
                int kh = c / 14, kw = c - kh * 14;
#pragma unroll
                for (int j = 0; j < 4; j++) {
                    int rr = tr * 16 + quad * 4 + j;
                    if (rr > 195) rr = 195;
                    float dh = b2f(sc[(w * 2 + 0) * 448 + (quad * 4 + j) * 28 +
                                      (rr / 14 - kh + 13)]);
                    float dw = b2f(sc[(w * 2 + 1) * 448 + (quad * 4 + j) * 28 +
                                      (rr % 14 - kw + 13)]);
                    sf[tc][j] = sf[tc][j] * 0.125f + dh + dw;
                }
            } else {
#pragma unroll
                for (int j = 0; j < 4; j++) sf[tc][j] = -30000.0f;
            }
        }
        f32x4 mx = sf[0];
#pragma unroll
        for (int tc = 1; tc < 13; tc++)
#pragma unroll
            for (int j = 0; j < 4; j++) mx[j] = fmaxf(mx[j], sf[tc][j]);
        for (int off = 1; off < 16; off <<= 1)
#pragma unroll
            for (int j = 0; j < 4; j++) mx[j] = fmaxf(mx[j], __shfl_xor(mx[j], off));
        f32x4 sum = (f32x4){0.f, 0.f, 0.f, 0.f};
#pragma unroll
        for (int tc = 0; tc < 13; tc++)
#pragma unroll
            for (int j = 0; j < 4; j++) {
                float p = __expf(sf[tc][j] - mx[j]);
                sf[tc][j] = p;
                sum[j] += p;
            }
        for (int off = 1; off < 16; off <<= 1)
#pragma unroll
            for (int j = 0; j < 4; j++) sum[j] += __shfl_xor(sum[j], off);
        f32x4 linv;
#pragma unroll
        for (int j = 0; j < 4; j++) linv[j] = 1.0f / sum[j];

        f32x4 oa[4];
#pragma unroll
        for (int tn = 0; tn < 4; tn++) oa[tn] = (f32x4){0.f, 0.f, 0.f, 0.f};
#pragma unroll
        for (int tc = 0; tc < 6; tc++) {
            int c = tc * 16 + l16;
#pragma unroll
            for (int j = 0; j < 4; j++)
                Ps[(w * 16 + quad * 4 + j) * 104 + c] = f2b(sf[tc][j]);
        }
#pragma unroll
        for (int ks = 0; ks < 3; ks++) {
            bf16x8 pf = *(const bf16x8*)&Ps[(w * 16 + l16) * 104 + ks * 32 + quad * 8];
#pragma unroll
            for (int tn = 0; tn < 4; tn++) {
                bf16x8 vf = *(const bf16x8*)&Vt[(tn * 16 + l16) * 200 + ks * 32 + quad * 8];
                oa[tn] = __builtin_amdgcn_mfma_f32_16x16x32_bf16(pf, vf, oa[tn], 0, 0, 0);
            }
        }
#pragma unroll
        for (int tc = 6; tc < 13; tc++) {
            int c = tc * 16 + l16;
            if (c < 196) {
#pragma unroll
                for (int j = 0; j < 4; j++)
                    Ps[(w * 16 + quad * 4 + j) * 104 + (c - 96)] = f2b(sf[tc][j]);
            }
        }
#pragma unroll
        for (int ks = 0; ks < 3; ks++) {
            bf16x8 pf = *(const bf16x8*)&Ps[(w * 16 + l16) * 104 + ks * 32 + quad * 8];
#pragma unroll
            for (int tn = 0; tn < 4; tn++) {
                bf16x8 vf = *(const bf16x8*)&Vt[(tn * 16 + l16) * 200 + 96 + ks * 32 + quad * 8];
                oa[tn] = __builtin_amdgcn_mfma_f32_16x16x32_bf16(pf, vf, oa[tn], 0, 0, 0);
            }
        }
        for (int kk = 192; kk < 196; kk++) {
            float pj[4];
#pragma unroll
            for (int j = 0; j < 4; j++)
                pj[j] = b2f(Ps[(w * 16 + quad * 4 + j) * 104 + 96 + (kk - 192)]);
#pragma unroll
            for (int tn = 0; tn < 4; tn++) {
                float vv = b2f(Vt[(tn * 16 + l16) * 200 + kk]);
#pragma unroll
                for (int j = 0; j < 4; j++) oa[tn][j] += pj[j] * vv;
            }
        }
#pragma unroll
        for (int j = 0; j < 4; j++) {
            int rr = tr * 16 + quad * 4 + j;
            if (rr < 196) {
                int gh = whh + rr / 14, gw = www + rr % 14;
                if (gh < 64 && gw < 64) {
                    long orow = (long)img * 4096 + gh * 64 + gw - orow0;
#pragma unroll
                    for (int tn = 0; tn < 4; tn++)
                        o_out[orow * 1024 + head * 64 + tn * 16 + l16] =
                            f2b(oa[tn][j] * linv[j]);
                }
            }
        }
    }
}

// ---------------- launch ----------------
extern "C" void kernel_launch(void* const* d_in, const int* in_sizes, int n_in,
                              void* d_out, int out_size, void* d_ws, size_t ws_size,
                              hipStream_t stream) {
    const float* x = (const float*)d_in[0];
    const float* n1s = (const float*)d_in[1];
    const float* n1b = (const float*)d_in[2];
    const float* qkvW = (const float*)d_in[3];
    const float* qkvB = (const float*)d_in[4];
    const float* relH = (const float*)d_in[5];
    const float* relW = (const float*)d_in[6];
    const float* projW = (const float*)d_in[7];
    const float* projB = (const float*)d_in[8];
    const float* n2s = (const float*)d_in[9];
    const float* n2b = (const float*)d_in[10];
    const float* fc1W = (const float*)d_in[11];
    const float* fc1B = (const float*)d_in[12];
    const float* fc2W = (const float*)d_in[13];
    const float* fc2B = (const float*)d_in[14];
    float* OUT = (float*)d_out;
    char* ws = (char*)d_ws;

    if (ws_size >= 221000000ULL) {
        // ---- FULL tier (peak 220.2 MB): 11 dispatches, gemm256 pipeline ----
        ushort* T0  = (ushort*)(ws);
        ushort* TP  = (ushort*)(ws + 6291456ULL);
        ushort* TF1 = (ushort*)(ws + 8388608ULL);
        ushort* TF2 = (ushort*)(ws + 16777216ULL);
        ushort* W0  = (ushort*)(ws + 25165824ULL);
        ushort* QKV = (ushort*)(ws + 65536000ULL);
        ushort* AO  = (ushort*)(ws + 186646528ULL);
        ushort* Z   = (ushort*)(ws + 25165824ULL);
        ushort* H   = (ushort*)(ws + 58720256ULL);

        transpose_w<<<dim3(96, 32), dim3(32, 8), 0, stream>>>(qkvW, T0, 1024, 3072);
        transpose_w<<<dim3(32, 32), dim3(32, 8), 0, stream>>>(projW, TP, 1024, 1024);
        transpose_w<<<dim3(128, 32), dim3(32, 8), 0, stream>>>(fc1W, TF1, 1024, 4096);
        transpose_w<<<dim3(32, 128), dim3(32, 8), 0, stream>>>(fc2W, TF2, 4096, 1024);
        ln_part_kernel<<<19712, 256, 0, stream>>>(x, n1s, n1b, W0, 0, 100);
        gemm256<0, ushort><<<924, 512, 0, stream>>>(W0, T0, qkvB, nullptr, QKV,
                                                    19712, 3072, 1024, 12);
        attn_kernel<<<dim3(100, 16), 256, 0, stream>>>(QKV, AO, relH, relW, 0, 0L);
        gemm256<2, float><<<256, 512, 0, stream>>>(AO, TP, projB, x, OUT,
                                                   16384, 1024, 1024, 4);
        ln_kernel<<<16384, 256, 0, stream>>>(OUT, n2s, n2b, Z);
        gemm256<1, ushort><<<1024, 512, 0, stream>>>(Z, TF1, fc1B, nullptr, H,
                                                     16384, 4096, 1024, 16);
        gemm256<2, float><<<256, 512, 0, stream>>>(H, TF2, fc2B, OUT, OUT,
                                                   16384, 1024, 4096, 4);
    } else if (ws_size >= 100000000ULL) {
        // ---- MID tier (peak 99.6 MB): proven round-0 path ----
        ushort* T0  = (ushort*)(ws);
        ushort* TP  = (ushort*)(ws + 6291456ULL);
        ushort* TF1 = (ushort*)(ws + 8388608ULL);
        ushort* TF2 = (ushort*)(ws + 16777216ULL);
        ushort* AO  = (ushort*)(ws + 25165824ULL);
        ushort* W0  = (ushort*)(ws + 58720256ULL);
        ushort* QKV = (ushort*)(ws + 68943872ULL);
        ushort* Z   = (ushort*)(ws + 25165824ULL);
        ushort* H   = (ushort*)(ws + 58720256ULL);

        transpose_w<<<dim3(96, 32), dim3(32, 8), 0, stream>>>(qkvW, T0, 1024, 3072);
        transpose_w<<<dim3(32, 32), dim3(32, 8), 0, stream>>>(projW, TP, 1024, 1024);
        transpose_w<<<dim3(128, 32), dim3(32, 8), 0, stream>>>(fc1W, TF1, 1024, 4096);
        transpose_w<<<dim3(32, 128), dim3(32, 8), 0, stream>>>(fc2W, TF2, 4096, 1024);
        for (int i = 0; i < 4; i++) {
            ln_part_kernel<<<4992, 256, 0, stream>>>(x, n1s, n1b, W0, i * 25, 25);
            gemm_bt<0, ushort><<<dim3(39, 24), 256, 0, stream>>>(W0, T0, qkvB, nullptr,
                                                                 QKV, 4992, 3072, 1024);
            attn_kernel<<<dim3(25, 16), 256, 0, stream>>>(QKV, AO, relH, relW, i * 25, 0L);
        }
        gemm_bt<2, float><<<dim3(128, 8), 256, 0, stream>>>(AO, TP, projB, x, OUT,
                                                            16384, 1024, 1024);
        for (int c = 0; c < 4; c++) {
            float* xc = OUT + (long)c * 4194304;
            ln_kernel<<<4096, 256, 0, stream>>>(xc, n2s, n2b, Z);
            gemm_bt<1, ushort><<<dim3(32, 32), 256, 0, stream>>>(Z, TF1, fc1B, nullptr, H,
                                                                 4096, 4096, 1024);
            gemm_bt<2, float><<<dim3(32, 8), 256, 0, stream>>>(H, TF2, fc2B, xc, xc,
                                                               4096, 1024, 4096);
        }
    } else {
        // ---- FALLBACK (proven 31.2 MB): round-0 path ----
        ushort* T0 = (ushort*)(ws);
        ushort* W0 = (ushort*)(ws + 6291456ULL);
        ushort* W1 = (ushort*)(ws + 16515072ULL);
        ushort* W2 = (ushort*)(ws + 22806528ULL);
        ushort* F1 = (ushort*)(ws);
        ushort* F2 = (ushort*)(ws + 8388608ULL);
        ushort* Z  = (ushort*)(ws + 16777216ULL);
        ushort* H  = (ushort*)(ws + 18874368ULL);

        transpose_w<<<dim3(96, 32), dim3(32, 8), 0, stream>>>(qkvW, T0, 1024, 3072);
        for (int i = 0; i < 4; i++) {
            const float* xi = x + (long)i * 4194304;
            ln_part_kernel<<<4992, 256, 0, stream>>>(x, n1s, n1b, W0, i * 25, 25);
            for (int g = 0; g < 5; g++) {
                gemm_bt<0, ushort><<<dim3(8, 24), 256, 0, stream>>>(
                    W0 + (long)g * 980 * 1024, T0, qkvB, nullptr, W1, 1024, 3072, 1024);
                attn_kernel<<<dim3(5, 16), 256, 0, stream>>>(W1, W2, relH, relW,
                                                             i * 25 + g * 5, (long)i * 4096);
            }
            transpose_w<<<dim3(32, 32), dim3(32, 8), 0, stream>>>(projW, W1, 1024, 1024);
            gemm_bt<2, float><<<dim3(32, 8), 256, 0, stream>>>(
                W2, W1, projB, xi, OUT + (long)i * 4194304, 4096, 1024, 1024);
        }
        transpose_w<<<dim3(128, 32), dim3(32, 8), 0, stream>>>(fc1W, F1, 1024, 4096);
        transpose_w<<<dim3(32, 128), dim3(32, 8), 0, stream>>>(fc2W, F2, 4096, 1024);
        for (int c = 0; c < 16; c++) {
            float* xc = OUT + (long)c * 1048576;
            ln_kernel<<<1024, 256, 0, stream>>>(xc, n2s, n2b, Z);
            gemm_bt<1, ushort><<<dim3(8, 32), 256, 0, stream>>>(Z, F1, fc1B, nullptr, H,
                                                                1024, 4096, 1024);
            gemm_bt<2, float><<<dim3(8, 8), 256, 0, stream>>>(H, F2, fc2B, xc, xc,
                                                              1024, 1024, 4096);
        }
    }
}

// Round 8
// 975.837 us; speedup vs baseline: 1.4646x; 1.0789x over previous
//
#include <hip/hip_runtime.h>

typedef __attribute__((ext_vector_type(8))) short bf16x8;
typedef __attribute__((ext_vector_type(4))) float f32x4;
typedef __attribute__((ext_vector_type(16))) float f32x16;

__device__ __forceinline__ float b2f(ushort u) {
    union { unsigned int i; float f; } v; v.i = ((unsigned int)u) << 16; return v.f;
}
__device__ __forceinline__ ushort f2b(float f) {
    union { float f; unsigned int i; } v; v.f = f;
    unsigned int i = v.i;
    return (ushort)((i + 0x7FFFu + ((i >> 16) & 1u)) >> 16);
}
__device__ __forceinline__ void glds16(const ushort* g, ushort* l) {
    __builtin_amdgcn_global_load_lds((const __attribute__((address_space(1))) void*)g,
                                     (__attribute__((address_space(3))) void*)l, 16, 0, 0);
}
// raw barrier with compiler memory fences (no implicit vmcnt/lgkm drain)
__device__ __forceinline__ void BARX() {
    asm volatile("" ::: "memory");
    __builtin_amdgcn_s_barrier();
    asm volatile("" ::: "memory");
}

// ---- LN2: x2(fp32 rows,1024) -> y (bf16) ----
__global__ __launch_bounds__(256) void ln_kernel(const float* __restrict__ x,
                                                 const float* __restrict__ sc,
                                                 const float* __restrict__ bi,
                                                 ushort* __restrict__ y) {
    __shared__ float red[8];
    long row = blockIdx.x;
    const float* xr = x + row * 1024;
    int t = threadIdx.x;
    float4 u = *(const float4*)(xr + t * 4);
    float s = u.x + u.y + u.z + u.w;
    float q = u.x * u.x + u.y * u.y + u.z * u.z + u.w * u.w;
    for (int off = 32; off > 0; off >>= 1) {
        s += __shfl_xor(s, off);
        q += __shfl_xor(q, off);
    }
    if ((t & 63) == 0) { red[t >> 6] = s; red[4 + (t >> 6)] = q; }
    __syncthreads();
    s = red[0] + red[1] + red[2] + red[3];
    q = red[4] + red[5] + red[6] + red[7];
    float mean = s * (1.0f / 1024.0f);
    float var = q * (1.0f / 1024.0f) - mean * mean;
    float rstd = rsqrtf(fmaxf(var, 0.0f) + 1e-6f);
    int c = t * 4;
    float o0 = (u.x - mean) * rstd * sc[c + 0] + bi[c + 0];
    float o1 = (u.y - mean) * rstd * sc[c + 1] + bi[c + 1];
    float o2 = (u.z - mean) * rstd * sc[c + 2] + bi[c + 2];
    float o3 = (u.w - mean) * rstd * sc[c + 3] + bi[c + 3];
    uint2 o;
    o.x = (unsigned int)f2b(o0) | ((unsigned int)f2b(o1) << 16);
    o.y = (unsigned int)f2b(o2) | ((unsigned int)f2b(o3) << 16);
    *(uint2*)(y + row * 1024 + c) = o;
}

// ---- fused LN1 + window partition ----
__global__ __launch_bounds__(256) void ln_part_kernel(const float* __restrict__ x,
                                                      const float* __restrict__ sc,
                                                      const float* __restrict__ bi,
                                                      ushort* __restrict__ wy,
                                                      int win_base, int nvalid) {
    __shared__ float red[8];
    int wt = blockIdx.x;
    int lwin = wt / 196, rr = wt % 196;
    int t = threadIdx.x;
    int valid = 0;
    long xrow = 0;
    if (lwin < nvalid) {
        int gwin = win_base + lwin;
        int img = gwin / 25, wrem = gwin % 25;
        int gh = (wrem / 5) * 14 + rr / 14;
        int gw = (wrem % 5) * 14 + rr % 14;
        if (gh < 64 && gw < 64) {
            valid = 1;
            xrow = (long)img * 4096 + gh * 64 + gw;
        }
    }
    uint2 o; o.x = 0u; o.y = 0u;
    if (valid) {
        const float* xr = x + xrow * 1024;
        float4 u = *(const float4*)(xr + t * 4);
        float s = u.x + u.y + u.z + u.w;
        float q = u.x * u.x + u.y * u.y + u.z * u.z + u.w * u.w;
        for (int off = 32; off > 0; off >>= 1) {
            s += __shfl_xor(s, off);
            q += __shfl_xor(q, off);
        }
        if ((t & 63) == 0) { red[t >> 6] = s; red[4 + (t >> 6)] = q; }
        __syncthreads();
        s = red[0] + red[1] + red[2] + red[3];
        q = red[4] + red[5] + red[6] + red[7];
        float mean = s * (1.0f / 1024.0f);
        float var = q * (1.0f / 1024.0f) - mean * mean;
        float rstd = rsqrtf(fmaxf(var, 0.0f) + 1e-6f);
        int c = t * 4;
        float o0 = (u.x - mean) * rstd * sc[c + 0] + bi[c + 0];
        float o1 = (u.y - mean) * rstd * sc[c + 1] + bi[c + 1];
        float o2 = (u.z - mean) * rstd * sc[c + 2] + bi[c + 2];
        float o3 = (u.w - mean) * rstd * sc[c + 3] + bi[c + 3];
        o.x = (unsigned int)f2b(o0) | ((unsigned int)f2b(o1) << 16);
        o.y = (unsigned int)f2b(o2) | ((unsigned int)f2b(o3) << 16);
    }
    *(uint2*)(wy + (long)wt * 1024 + t * 4) = o;
}

// ---- transpose + cast: in fp32 (K,N) -> out bf16 (N,K) ----
__global__ void transpose_w(const float* __restrict__ in, ushort* __restrict__ out,
                            int K, int N) {
    __shared__ float tile[32][33];
    int n0 = blockIdx.x * 32, k0 = blockIdx.y * 32;
    int tx = threadIdx.x, ty = threadIdx.y;
    for (int i = 0; i < 32; i += 8)
        tile[ty + i][tx] = in[(long)(k0 + ty + i) * N + n0 + tx];
    __syncthreads();
    for (int i = 0; i < 32; i += 8)
        out[(long)(n0 + ty + i) * K + k0 + tx] = f2b(tile[tx][ty + i]);
}

// ---- legacy GEMM (m97 structure, proven) ----
template <int FLAGS, typename OT>
__global__ __launch_bounds__(256) void gemm_bt(const ushort* __restrict__ A,
                                               const ushort* __restrict__ Bt,
                                               const float* __restrict__ bias,
                                               const float* __restrict__ resid,
                                               OT* __restrict__ out,
                                               int M, int N, int K) {
    __shared__ __align__(16) ushort As[128 * 32];
    __shared__ __align__(16) ushort Bs[128 * 32];
    const int tid = threadIdx.x;
    const int lane = tid & 63, w = tid >> 6;
    const int wm = (w >> 1) * 64, wn = (w & 1) * 64;
    const int quad = lane >> 4, l16 = lane & 15;
    const int bm = blockIdx.x * 128, bn = blockIdx.y * 128;
    const int r = tid >> 2, kc = (tid & 3) * 8;
    f32x4 acc[4][4];
#pragma unroll
    for (int i = 0; i < 4; i++)
#pragma unroll
        for (int j = 0; j < 4; j++) acc[i][j] = (f32x4){0.f, 0.f, 0.f, 0.f};
    const ushort* Ag = A + (long)(bm + r) * K + kc;
    const ushort* Bg = Bt + (long)(bn + r) * K + kc;
    ushort* AsW = As + w * 512;
    ushort* BsW = Bs + w * 512;
    for (int k0 = 0; k0 < K; k0 += 32) {
        __syncthreads();
        glds16(Ag + k0, AsW);
        glds16(Ag + (long)64 * K + k0, AsW + 2048);
        glds16(Bg + k0, BsW);
        glds16(Bg + (long)64 * K + k0, BsW + 2048);
        __syncthreads();
        bf16x8 afr[4], bfr[4];
#pragma unroll
        for (int t = 0; t < 4; t++) {
            afr[t] = *(const bf16x8*)&As[(wm + t * 16 + l16) * 32 + quad * 8];
            bfr[t] = *(const bf16x8*)&Bs[(wn + t * 16 + l16) * 32 + quad * 8];
        }
#pragma unroll
        for (int tm = 0; tm < 4; tm++)
#pragma unroll
            for (int tn = 0; tn < 4; tn++)
                acc[tm][tn] = __builtin_amdgcn_mfma_f32_16x16x32_bf16(afr[tm], bfr[tn],
                                                                     acc[tm][tn], 0, 0, 0);
    }
#pragma unroll
    for (int tm = 0; tm < 4; tm++) {
#pragma unroll
        for (int j = 0; j < 4; j++) {
            int gm = bm + wm + tm * 16 + quad * 4 + j;
#pragma unroll
            for (int tn = 0; tn < 4; tn++) {
                int gn = bn + wn + tn * 16 + l16;
                float v = acc[tm][tn][j] + bias[gn];
                if (FLAGS & 1) v = 0.5f * v * (1.0f + erff(v * 0.70710678118654752f));
                if (FLAGS & 2) v += resid[(long)gm * N + gn];
                if (sizeof(OT) == 4) out[(long)gm * N + gn] = (OT)v;
                else out[(long)gm * N + gn] = (OT)f2b(v);
            }
        }
    }
}

// ======== 128x128 GEMM, 32x32x16 engine, ring-2, 32 KiB LDS, 4 blocks/CU ========
// The per-block global_load_lds throughput wall (~9.5 B/cyc/block, measured across
// r2/r3/r5/r7+m97) makes blocks/CU the lever: 256 threads (4 waves of 64x64 out),
// acc[2][2] f32x16 = 64 AGPRs, launch_bounds(256,4) -> 16 waves/CU = 4 blocks.
// Schedule = proven m97 cadence: stage tile t+1 at top of tile t (4 glds/wave),
// counted lgkm inside the tile, vmcnt(0)+barrier at tile end (drain target was
// issued a full tile earlier; co-resident blocks cover the stall - m114 overlap).
// Addressing/swizzle copied from the twice-refchecked r5 32x32 kernel (64B rows,
// 4-slot XOR swz(r)=(r&3)^((r>>2)&1) on both stage-source and read slots).
#define DSR(dst, addr, imm) \
    asm volatile("ds_read_b128 %0, %1 offset:%2" : "=&v"(dst) : "v"(addr), "n"(imm));

#define MFMA32(mf, nf, a, b) \
    acc[mf][nf] = __builtin_amdgcn_mfma_f32_32x32x16_bf16(a, b, acc[mf][nf], 0, 0, 0);

#define RDK0(c) \
    DSR(a0, a_k0, (c) * 8192 + 0)    DSR(a1, a_k0, (c) * 8192 + 2048) \
    DSR(b0, b_k0, (c) * 8192 + 0)    DSR(b1, b_k0, (c) * 8192 + 2048)
#define RDK1(c) \
    DSR(A0, a_k1, (c) * 8192 + 0)    DSR(A1, a_k1, (c) * 8192 + 2048) \
    DSR(B0, b_k1, (c) * 8192 + 0)    DSR(B1, b_k1, (c) * 8192 + 2048)

#define MFK0 \
    MFMA32(0, 0, a0, b0) MFMA32(0, 1, a0, b1) MFMA32(1, 0, a1, b0) MFMA32(1, 1, a1, b1)
#define MFK1 \
    MFMA32(0, 0, A0, B0) MFMA32(0, 1, A0, B1) MFMA32(1, 0, A1, B0) MFMA32(1, 1, A1, B1)

#define STAGE4(ts, dbuf) \
    glds16(Ag + (long)(ts) * 32, &As[dbuf][w * 512]); \
    glds16(Ag2 + (long)(ts) * 32, &As[dbuf][w * 512 + 2048]); \
    glds16(Bg + (long)(ts) * 32, &Bs[dbuf][w * 512]); \
    glds16(Bg2 + (long)(ts) * 32, &Bs[dbuf][w * 512 + 2048]);

#define BODY(c, ts, STG) do {                                                  \
    if (STG) { STAGE4((ts) + 1, (c) ^ 1) }                                     \
    __builtin_amdgcn_sched_barrier(0);                                         \
    RDK0(c) RDK1(c)                                                            \
    asm volatile("s_waitcnt lgkmcnt(4)" ::: "memory");                         \
    __builtin_amdgcn_sched_barrier(0);                                         \
    __builtin_amdgcn_s_setprio(1); MFK0 __builtin_amdgcn_s_setprio(0);         \
    __builtin_amdgcn_sched_barrier(0);                                         \
    asm volatile("s_waitcnt lgkmcnt(0)" ::: "memory");                         \
    __builtin_amdgcn_sched_barrier(0);                                         \
    __builtin_amdgcn_s_setprio(1); MFK1 __builtin_amdgcn_s_setprio(0);         \
    __builtin_amdgcn_sched_barrier(0);                                         \
    if (STG) { asm volatile("s_waitcnt vmcnt(0)" ::: "memory"); BARX(); }      \
} while (0)

template <int FLAGS, typename OT>
__global__ __launch_bounds__(256, 4) void gemm128(const ushort* __restrict__ A,
                                                  const ushort* __restrict__ Bt,
                                                  const float* __restrict__ bias,
                                                  const float* __restrict__ resid,
                                                  OT* __restrict__ out,
                                                  int M, int N, int K, int nbn) {
    __shared__ __align__(64) ushort As[2][4096];   // 2 x (128 rows x 32 halfs) = 16 KB
    __shared__ __align__(64) ushort Bs[2][4096];   // 16 KB
    // bijective XCD swizzle (m204)
    const int nwg = gridDim.x;
    const int orig = blockIdx.x;
    const int q8 = nwg >> 3, r8 = nwg & 7;
    const int xcd = orig & 7, sub = orig >> 3;
    const int wgid = (xcd < r8 ? xcd * (q8 + 1) : r8 * (q8 + 1) + (xcd - r8) * q8) + sub;
    const int bm = (wgid / nbn) * 128, bn = (wgid % nbn) * 128;

    const int tid = threadIdx.x;
    const int lane = tid & 63, w = tid >> 6;          // 4 waves
    const int l31 = lane & 31, hi = lane >> 5;
    const int wm = (w >> 1) * 64, wn = (w & 1) * 64;  // 2M x 2N wave grid

    // staging: per glds a wave writes 16 rows x 64B linearly; source column slot
    // pre-swizzled with swz(r)=(r&3)^((r>>2)&1) (rule 21; lane-only expression).
    const int ly = lane >> 2;                          // 0..15
    const int c_st = (((lane & 3) ^ ((lane >> 2) & 3) ^ ((lane >> 4) & 1)) << 3);
    const ushort* Ag = A + (long)(bm + w * 16 + ly) * K + c_st;
    const ushort* Ag2 = Ag + (long)64 * K;
    const ushort* Bg = Bt + (long)(bn + w * 16 + ly) * K + c_st;
    const ushort* Bg2 = Bg + (long)64 * K;

    // read addressing (32x32x16 frags): row = base+l31, k-span hi*8 (+16 for k1);
    // physical 16B slot = logical(kh*2+hi) ^ swz(row) -- r5's verified formulas.
    const int swz = (lane & 3) ^ ((lane >> 2) & 1);
    const int s0 = swz & 1, s1 = swz >> 1;
    const int slot_k0 = (((0 ^ s1) << 1) | (hi ^ s0)) << 4;    // bytes
    const int slot_k1 = (((1 ^ s1) << 1) | (hi ^ s0)) << 4;
    const unsigned As0 =
        (unsigned)(size_t)(__attribute__((address_space(3))) ushort*)&As[0][0];
    const unsigned Bs0 =
        (unsigned)(size_t)(__attribute__((address_space(3))) ushort*)&Bs[0][0];
    const unsigned a_k0 = As0 + (unsigned)((wm + l31) * 64 + slot_k0);
    const unsigned a_k1 = As0 + (unsigned)((wm + l31) * 64 + slot_k1);
    const unsigned b_k0 = Bs0 + (unsigned)((wn + l31) * 64 + slot_k0);
    const unsigned b_k1 = Bs0 + (unsigned)((wn + l31) * 64 + slot_k1);

    f32x16 acc[2][2];
#pragma unroll
    for (int i = 0; i < 2; i++)
#pragma unroll
        for (int j = 0; j < 2; j++)
#pragma unroll
            for (int e = 0; e < 16; e++) acc[i][j][e] = 0.f;

    bf16x8 a0, a1, b0, b1;   // k0-half frags (A mf0/mf1, B nf0/nf1)
    bf16x8 A0, A1, B0, B1;   // k1-half frags

    // prologue: stage tile 0 into buf 0, publish to all waves
    STAGE4(0, 0)
    __builtin_amdgcn_sched_barrier(0);
    asm volatile("s_waitcnt vmcnt(0)" ::: "memory");
    BARX();

    const int nt = K >> 5;  // 32 (K=1024) or 128 (K=4096); even, >= 2
    for (int t = 0; t < nt - 2; t += 2) {
        BODY(0, t, 1);
        BODY(1, t + 1, 1);
    }
    BODY(0, nt - 2, 1);   // stages tile nt-1 into buf 1
    BODY(1, nt - 1, 0);   // final, no staging

    // epilogue: C frag layout col=lane&31, row=(reg&3)+8*(reg>>2)+4*hi  [m74/m101]
#pragma unroll
    for (int mf = 0; mf < 2; mf++) {
#pragma unroll
        for (int nf = 0; nf < 2; nf++) {
            const int gn = bn + wn + nf * 32 + l31;
#pragma unroll
            for (int q = 0; q < 4; q++) {
#pragma unroll
                for (int j = 0; j < 4; j++) {
                    const int gm = bm + wm + mf * 32 + q * 8 + j + 4 * hi;
                    const long ro = (long)gm * N;
                    float v = acc[mf][nf][q * 4 + j] + bias[gn];
                    if (FLAGS & 1) v = 0.5f * v * (1.0f + erff(v * 0.70710678118654752f));
                    if (FLAGS & 2) v += resid[ro + gn];
                    if (sizeof(OT) == 4) out[ro + gn] = (OT)v;
                    else out[ro + gn] = (OT)f2b(v);
                }
            }
        }
    }
}

// ---- attention per (window, head): rel-pos via MFMA, 46 KB LDS ----
__global__ __launch_bounds__(256) void attn_kernel(const ushort* __restrict__ qkv,
                                                   ushort* __restrict__ o_out,
                                                   const float* __restrict__ relH,
                                                   const float* __restrict__ relW,
                                                   int win0, long orow0) {
    __shared__ __align__(16) ushort Vt[64 * 200];
    __shared__ __align__(16) ushort Ps[64 * 104];
    __shared__ __align__(16) ushort sc[8 * 448];
    const int head = blockIdx.y;
    const long qbase = (long)blockIdx.x * 196 * 3072 + head * 64;
    const int gwin = win0 + blockIdx.x;
    const int img = gwin / 25, wrem = gwin % 25;
    const int whh = (wrem / 5) * 14, www = (wrem % 5) * 14;
    const int tid = threadIdx.x, lane = tid & 63, w = tid >> 6;
    const int quad = lane >> 4, l16 = lane & 15;

    for (int idx = tid; idx < 196 * 64; idx += 256) {
        int k = idx >> 6, d = idx & 63;
        Vt[d * 200 + k] = qkv[qbase + 2048 + (long)k * 3072 + d];
    }
    __syncthreads();

    bf16x8 bH[2][2], bW[2][2];
#pragma unroll
    for (int nt = 0; nt < 2; nt++) {
        int n = nt * 16 + l16;
#pragma unroll
        for (int kt = 0; kt < 2; kt++) {
            bf16x8 rh = (bf16x8){0, 0, 0, 0, 0, 0, 0, 0};
            bf16x8 rw = (bf16x8){0, 0, 0, 0, 0, 0, 0, 0};
            if (n < 27) {
                const float* ph = relH + n * 64 + kt * 32 + quad * 8;
                const float* pw = relW + n * 64 + kt * 32 + quad * 8;
#pragma unroll
                for (int e = 0; e < 8; e++) {
                    rh[e] = (short)f2b(ph[e]);
                    rw[e] = (short)f2b(pw[e]);
                }
            }
            bH[nt][kt] = rh;
            bW[nt][kt] = rw;
        }
    }

    for (int tr = w; tr < 13; tr += 4) {
        int qrow = tr * 16 + l16;
        if (qrow > 195) qrow = 195;
        bf16x8 qf0 = *(const bf16x8*)(qkv + qbase + (long)qrow * 3072 + quad * 8);
        bf16x8 qf1 = *(const bf16x8*)(qkv + qbase + (long)qrow * 3072 + 32 + quad * 8);

#pragma unroll
        for (int tab = 0; tab < 2; tab++) {
#pragma unroll
            for (int nt = 0; nt < 2; nt++) {
                f32x4 a = (f32x4){0.f, 0.f, 0.f, 0.f};
                a = __builtin_amdgcn_mfma_f32_16x16x32_bf16(qf0, tab ? bW[nt][0] : bH[nt][0],
                                                            a, 0, 0, 0);
                a = __builtin_amdgcn_mfma_f32_16x16x32_bf16(qf1, tab ? bW[nt][1] : bH[nt][1],
                                                            a, 0, 0, 0);
                int col = nt * 16 + l16;
                if (col < 27) {
#pragma unroll
                    for (int j = 0; j < 4; j++)
                        sc[(w * 2 + tab) * 448 + (quad * 4 + j) * 28 + col] = f2b(a[j]);
                }
            }
        }

        f32x4 sf[13];
#pragma unroll
        for (int tc = 0; tc < 13; tc++) {
            int krow = tc * 16 + l16;
            if (krow > 195) krow = 195;
            const ushort* kp = qkv + qbase + 1024 + (long)krow * 3072 + quad * 8;
            bf16x8 kf0 = *(const bf16x8*)kp;
            bf16x8 kf1 = *(const bf16x8*)(kp + 32);
            f32x4 s = (f32x4){0.f, 0.f, 0.f, 0.f};
            s = __builtin_amdgcn_mfma_f32_16x16x32_bf16(qf0, kf0, s, 0, 0, 0);
            s = __builtin_amdgcn_mfma_f32_16x16x32_bf16(qf1, kf1, s, 0, 0, 0);
            sf[tc] = s;
        }
#pragma unroll
        for (int tc = 0; tc < 13; tc++) {
            int c = tc * 16 + l16;
            if (c < 196) {
                int kh = c / 14, kw = c - kh * 14;
#pragma unroll
                for (int j = 0; j < 4; j++) {
                    int rr = tr * 16 + quad * 4 + j;
                    if (rr > 195) rr = 195;
                    float dh = b2f(sc[(w * 2 + 0) * 448 + (quad * 4 + j) * 28 +
                                      (rr / 14 - kh + 13)]);
                    float dw = b2f(sc[(w * 2 + 1) * 448 + (quad * 4 + j) * 28 +
                                      (rr % 14 - kw + 13)]);
                    sf[tc][j] = sf[tc][j] * 0.125f + dh + dw;
                }
            } else {
#pragma unroll
                for (int j = 0; j < 4; j++) sf[tc][j] = -30000.0f;
            }
        }
        f32x4 mx = sf[0];
#pragma unroll
        for (int tc = 1; tc < 13; tc++)
#pragma unroll
            for (int j = 0; j < 4; j++) mx[j] = fmaxf(mx[j], sf[tc][j]);
        for (int off = 1; off < 16; off <<= 1)
#pragma unroll
            for (int j = 0; j < 4; j++) mx[j] = fmaxf(mx[j], __shfl_xor(mx[j], off));
        f32x4 sum = (f32x4){0.f, 0.f, 0.f, 0.f};
#pragma unroll
        for (int tc = 0; tc < 13; tc++)
#pragma unroll
            for (int j = 0; j < 4; j++) {
                float p = __expf(sf[tc][j] - mx[j]);
                sf[tc][j] = p;
                sum[j] += p;
            }
        for (int off = 1; off < 16; off <<= 1)
#pragma unroll
            for (int j = 0; j < 4; j++) sum[j] += __shfl_xor(sum[j], off);
        f32x4 linv;
#pragma unroll
        for (int j = 0; j < 4; j++) linv[j] = 1.0f / sum[j];

        f32x4 oa[4];
#pragma unroll
        for (int tn = 0; tn < 4; tn++) oa[tn] = (f32x4){0.f, 0.f, 0.f, 0.f};
#pragma unroll
        for (int tc = 0; tc < 6; tc++) {
            int c = tc * 16 + l16;
#pragma unroll
            for (int j = 0; j < 4; j++)
                Ps[(w * 16 + quad * 4 + j) * 104 + c] = f2b(sf[tc][j]);
        }
#pragma unroll
        for (int ks = 0; ks < 3; ks++) {
            bf16x8 pf = *(const bf16x8*)&Ps[(w * 16 + l16) * 104 + ks * 32 + quad * 8];
#pragma unroll
            for (int tn = 0; tn < 4; tn++) {
                bf16x8 vf = *(const bf16x8*)&Vt[(tn * 16 + l16) * 200 + ks * 32 + quad * 8];
                oa[tn] = __builtin_amdgcn_mfma_f32_16x16x32_bf16(pf, vf, oa[tn], 0, 0, 0);
            }
        }
#pragma unroll
        for (int tc = 6; tc < 13; tc++) {
            int c = tc * 16 + l16;
            if (c < 196) {
#pragma unroll
                for (int j = 0; j < 4; j++)
                    Ps[(w * 16 + quad * 4 + j) * 104 + (c - 96)] = f2b(sf[tc][j]);
            }
        }
#pragma unroll
        for (int ks = 0; ks < 3; ks++) {
            bf16x8 pf = *(const bf16x8*)&Ps[(w * 16 + l16) * 104 + ks * 32 + quad * 8];
#pragma unroll
            for (int tn = 0; tn < 4; tn++) {
                bf16x8 vf = *(const bf16x8*)&Vt[(tn * 16 + l16) * 200 + 96 + ks * 32 + quad * 8];
                oa[tn] = __builtin_amdgcn_mfma_f32_16x16x32_bf16(pf, vf, oa[tn], 0, 0, 0);
            }
        }
        for (int kk = 192; kk < 196; kk++) {
            float pj[4];
#pragma unroll
            for (int j = 0; j < 4; j++)
                pj[j] = b2f(Ps[(w * 16 + quad * 4 + j) * 104 + 96 + (kk - 192)]);
#pragma unroll
            for (int tn = 0; tn < 4; tn++) {
                float vv = b2f(Vt[(tn * 16 + l16) * 200 + kk]);
#pragma unroll
                for (int j = 0; j < 4; j++) oa[tn][j] += pj[j] * vv;
            }
        }
#pragma unroll
        for (int j = 0; j < 4; j++) {
            int rr = tr * 16 + quad * 4 + j;
            if (rr < 196) {
                int gh = whh + rr / 14, gw = www + rr % 14;
                if (gh < 64 && gw < 64) {
                    long orow = (long)img * 4096 + gh * 64 + gw - orow0;
#pragma unroll
                    for (int tn = 0; tn < 4; tn++)
                        o_out[orow * 1024 + head * 64 + tn * 16 + l16] =
                            f2b(oa[tn][j] * linv[j]);
                }
            }
        }
    }
}

// ---------------- launch ----------------
extern "C" void kernel_launch(void* const* d_in, const int* in_sizes, int n_in,
                              void* d_out, int out_size, void* d_ws, size_t ws_size,
                              hipStream_t stream) {
    const float* x = (const float*)d_in[0];
    const float* n1s = (const float*)d_in[1];
    const float* n1b = (const float*)d_in[2];
    const float* qkvW = (const float*)d_in[3];
    const float* qkvB = (const float*)d_in[4];
    const float* relH = (const float*)d_in[5];
    const float* relW = (const float*)d_in[6];
    const float* projW = (const float*)d_in[7];
    const float* projB = (const float*)d_in[8];
    const float* n2s = (const float*)d_in[9];
    const float* n2b = (const float*)d_in[10];
    const float* fc1W = (const float*)d_in[11];
    const float* fc1B = (const float*)d_in[12];
    const float* fc2W = (const float*)d_in[13];
    const float* fc2B = (const float*)d_in[14];
    float* OUT = (float*)d_out;
    char* ws = (char*)d_ws;

    if (ws_size >= 221000000ULL) {
        // ---- FULL tier (peak 220.2 MB): 11 dispatches, gemm128 pipeline ----
        ushort* T0  = (ushort*)(ws);
        ushort* TP  = (ushort*)(ws + 6291456ULL);
        ushort* TF1 = (ushort*)(ws + 8388608ULL);
        ushort* TF2 = (ushort*)(ws + 16777216ULL);
        ushort* W0  = (ushort*)(ws + 25165824ULL);
        ushort* QKV = (ushort*)(ws + 65536000ULL);
        ushort* AO  = (ushort*)(ws + 186646528ULL);
        ushort* Z   = (ushort*)(ws + 25165824ULL);
        ushort* H   = (ushort*)(ws + 58720256ULL);

        transpose_w<<<dim3(96, 32), dim3(32, 8), 0, stream>>>(qkvW, T0, 1024, 3072);
        transpose_w<<<dim3(32, 32), dim3(32, 8), 0, stream>>>(projW, TP, 1024, 1024);
        transpose_w<<<dim3(128, 32), dim3(32, 8), 0, stream>>>(fc1W, TF1, 1024, 4096);
        transpose_w<<<dim3(32, 128), dim3(32, 8), 0, stream>>>(fc2W, TF2, 4096, 1024);
        ln_part_kernel<<<19712, 256, 0, stream>>>(x, n1s, n1b, W0, 0, 100);
        gemm128<0, ushort><<<3696, 256, 0, stream>>>(W0, T0, qkvB, nullptr, QKV,
                                                     19712, 3072, 1024, 24);
        attn_kernel<<<dim3(100, 16), 256, 0, stream>>>(QKV, AO, relH, relW, 0, 0L);
        gemm128<2, float><<<1024, 256, 0, stream>>>(AO, TP, projB, x, OUT,
                                                    16384, 1024, 1024, 8);
        ln_kernel<<<16384, 256, 0, stream>>>(OUT, n2s, n2b, Z);
        gemm128<1, ushort><<<4096, 256, 0, stream>>>(Z, TF1, fc1B, nullptr, H,
                                                     16384, 4096, 1024, 32);
        gemm128<2, float><<<1024, 256, 0, stream>>>(H, TF2, fc2B, OUT, OUT,
                                                    16384, 1024, 4096, 8);
    } else if (ws_size >= 100000000ULL) {
        // ---- MID tier (peak 99.6 MB): proven round-0 path ----
        ushort* T0  = (ushort*)(ws);
        ushort* TP  = (ushort*)(ws + 6291456ULL);
        ushort* TF1 = (ushort*)(ws + 8388608ULL);
        ushort* TF2 = (ushort*)(ws + 16777216ULL);
        ushort* AO  = (ushort*)(ws + 25165824ULL);
        ushort* W0  = (ushort*)(ws + 58720256ULL);
        ushort* QKV = (ushort*)(ws + 68943872ULL);
        ushort* Z   = (ushort*)(ws + 25165824ULL);
        ushort* H   = (ushort*)(ws + 58720256ULL);

        transpose_w<<<dim3(96, 32), dim3(32, 8), 0, stream>>>(qkvW, T0, 1024, 3072);
        transpose_w<<<dim3(32, 32), dim3(32, 8), 0, stream>>>(projW, TP, 1024, 1024);
        transpose_w<<<dim3(128, 32), dim3(32, 8), 0, stream>>>(fc1W, TF1, 1024, 4096);
        transpose_w<<<dim3(32, 128), dim3(32, 8), 0, stream>>>(fc2W, TF2, 4096, 1024);
        for (int i = 0; i < 4; i++) {
            ln_part_kernel<<<4992, 256, 0, stream>>>(x, n1s, n1b, W0, i * 25, 25);
            gemm_bt<0, ushort><<<dim3(39, 24), 256, 0, stream>>>(W0, T0, qkvB, nullptr,
                                                                 QKV, 4992, 3072, 1024);
            attn_kernel<<<dim3(25, 16), 256, 0, stream>>>(QKV, AO, relH, relW, i * 25, 0L);
        }
        gemm_bt<2, float><<<dim3(128, 8), 256, 0, stream>>>(AO, TP, projB, x, OUT,
                                                            16384, 1024, 1024);
        for (int c = 0; c < 4; c++) {
            float* xc = OUT + (long)c * 4194304;
            ln_kernel<<<4096, 256, 0, stream>>>(xc, n2s, n2b, Z);
            gemm_bt<1, ushort><<<dim3(32, 32), 256, 0, stream>>>(Z, TF1, fc1B, nullptr, H,
                                                                 4096, 4096, 1024);
            gemm_bt<2, float><<<dim3(32, 8), 256, 0, stream>>>(H, TF2, fc2B, xc, xc,
                                                               4096, 1024, 4096);
        }
    } else {
        // ---- FALLBACK (proven 31.2 MB): round-0 path ----
        ushort* T0 = (ushort*)(ws);
        ushort* W0 = (ushort*)(ws + 6291456ULL);
        ushort* W1 = (ushort*)(ws + 16515072ULL);
        ushort* W2 = (ushort*)(ws + 22806528ULL);
        ushort* F1 = (ushort*)(ws);
        ushort* F2 = (ushort*)(ws + 8388608ULL);
        ushort* Z  = (ushort*)(ws + 16777216ULL);
        ushort* H  = (ushort*)(ws + 18874368ULL);

        transpose_w<<<dim3(96, 32), dim3(32, 8), 0, stream>>>(qkvW, T0, 1024, 3072);
        for (int i = 0; i < 4; i++) {
            const float* xi = x + (long)i * 4194304;
            ln_part_kernel<<<4992, 256, 0, stream>>>(x, n1s, n1b, W0, i * 25, 25);
            for (int g = 0; g < 5; g++) {
                gemm_bt<0, ushort><<<dim3(8, 24), 256, 0, stream>>>(
                    W0 + (long)g * 980 * 1024, T0, qkvB, nullptr, W1, 1024, 3072, 1024);
                attn_kernel<<<dim3(5, 16), 256, 0, stream>>>(W1, W2, relH, relW,
                                                             i * 25 + g * 5, (long)i * 4096);
            }
            transpose_w<<<dim3(32, 32), dim3(32, 8), 0, stream>>>(projW, W1, 1024, 1024);
            gemm_bt<2, float><<<dim3(32, 8), 256, 0, stream>>>(
                W2, W1, projB, xi, OUT + (long)i * 4194304, 4096, 1024, 1024);
        }
        transpose_w<<<dim3(128, 32), dim3(32, 8), 0, stream>>>(fc1W, F1, 1024, 4096);
        transpose_w<<<dim3(32, 128), dim3(32, 8), 0, stream>>>(fc2W, F2, 4096, 1024);
        for (int c = 0; c < 16; c++) {
            float* xc = OUT + (long)c * 1048576;
            ln_kernel<<<1024, 256, 0, stream>>>(xc, n2s, n2b, Z);
            gemm_bt<1, ushort><<<dim3(8, 32), 256, 0, stream>>>(Z, F1, fc1B, nullptr, H,
                                                                1024, 4096, 1024);
            gemm_bt<2, float><<<dim3(8, 8), 256, 0, stream>>>(H, F2, fc2B, xc, xc,
                                                              1024, 1024, 4096);
        }
    }
}

// Round 9
// 943.276 us; speedup vs baseline: 1.5152x; 1.0345x over previous
//
#include <hip/hip_runtime.h>

typedef __attribute__((ext_vector_type(8))) short bf16x8;
typedef __attribute__((ext_vector_type(4))) float f32x4;
typedef __attribute__((ext_vector_type(16))) float f32x16;

__device__ __forceinline__ float b2f(ushort u) {
    union { unsigned int i; float f; } v; v.i = ((unsigned int)u) << 16; return v.f;
}
__device__ __forceinline__ ushort f2b(float f) {
    union { float f; unsigned int i; } v; v.f = f;
    unsigned int i = v.i;
    return (ushort)((i + 0x7FFFu + ((i >> 16) & 1u)) >> 16);
}
__device__ __forceinline__ void glds16(const ushort* g, ushort* l) {
    __builtin_amdgcn_global_load_lds((const __attribute__((address_space(1))) void*)g,
                                     (__attribute__((address_space(3))) void*)l, 16, 0, 0);
}
// raw barrier with compiler memory fences (no implicit vmcnt/lgkm drain)
__device__ __forceinline__ void BARX() {
    asm volatile("" ::: "memory");
    __builtin_amdgcn_s_barrier();
    asm volatile("" ::: "memory");
}

// ---- LN2: x2(fp32 rows,1024) -> y (bf16) ----
__global__ __launch_bounds__(256) void ln_kernel(const float* __restrict__ x,
                                                 const float* __restrict__ sc,
                                                 const float* __restrict__ bi,
                                                 ushort* __restrict__ y) {
    __shared__ float red[8];
    long row = blockIdx.x;
    const float* xr = x + row * 1024;
    int t = threadIdx.x;
    float4 u = *(const float4*)(xr + t * 4);
    float s = u.x + u.y + u.z + u.w;
    float q = u.x * u.x + u.y * u.y + u.z * u.z + u.w * u.w;
    for (int off = 32; off > 0; off >>= 1) {
        s += __shfl_xor(s, off);
        q += __shfl_xor(q, off);
    }
    if ((t & 63) == 0) { red[t >> 6] = s; red[4 + (t >> 6)] = q; }
    __syncthreads();
    s = red[0] + red[1] + red[2] + red[3];
    q = red[4] + red[5] + red[6] + red[7];
    float mean = s * (1.0f / 1024.0f);
    float var = q * (1.0f / 1024.0f) - mean * mean;
    float rstd = rsqrtf(fmaxf(var, 0.0f) + 1e-6f);
    int c = t * 4;
    float o0 = (u.x - mean) * rstd * sc[c + 0] + bi[c + 0];
    float o1 = (u.y - mean) * rstd * sc[c + 1] + bi[c + 1];
    float o2 = (u.z - mean) * rstd * sc[c + 2] + bi[c + 2];
    float o3 = (u.w - mean) * rstd * sc[c + 3] + bi[c + 3];
    uint2 o;
    o.x = (unsigned int)f2b(o0) | ((unsigned int)f2b(o1) << 16);
    o.y = (unsigned int)f2b(o2) | ((unsigned int)f2b(o3) << 16);
    *(uint2*)(y + row * 1024 + c) = o;
}

// ---- fused LN1 + window partition ----
__global__ __launch_bounds__(256) void ln_part_kernel(const float* __restrict__ x,
                                                      const float* __restrict__ sc,
                                                      const float* __restrict__ bi,
                                                      ushort* __restrict__ wy,
                                                      int win_base, int nvalid) {
    __shared__ float red[8];
    int wt = blockIdx.x;
    int lwin = wt / 196, rr = wt % 196;
    int t = threadIdx.x;
    int valid = 0;
    long xrow = 0;
    if (lwin < nvalid) {
        int gwin = win_base + lwin;
        int img = gwin / 25, wrem = gwin % 25;
        int gh = (wrem / 5) * 14 + rr / 14;
        int gw = (wrem % 5) * 14 + rr % 14;
        if (gh < 64 && gw < 64) {
            valid = 1;
            xrow = (long)img * 4096 + gh * 64 + gw;
        }
    }
    uint2 o; o.x = 0u; o.y = 0u;
    if (valid) {
        const float* xr = x + xrow * 1024;
        float4 u = *(const float4*)(xr + t * 4);
        float s = u.x + u.y + u.z + u.w;
        float q = u.x * u.x + u.y * u.y + u.z * u.z + u.w * u.w;
        for (int off = 32; off > 0; off >>= 1) {
            s += __shfl_xor(s, off);
            q += __shfl_xor(q, off);
        }
        if ((t & 63) == 0) { red[t >> 6] = s; red[4 + (t >> 6)] = q; }
        __syncthreads();
        s = red[0] + red[1] + red[2] + red[3];
        q = red[4] + red[5] + red[6] + red[7];
        float mean = s * (1.0f / 1024.0f);
        float var = q * (1.0f / 1024.0f) - mean * mean;
        float rstd = rsqrtf(fmaxf(var, 0.0f) + 1e-6f);
        int c = t * 4;
        float o0 = (u.x - mean) * rstd * sc[c + 0] + bi[c + 0];
        float o1 = (u.y - mean) * rstd * sc[c + 1] + bi[c + 1];
        float o2 = (u.z - mean) * rstd * sc[c + 2] + bi[c + 2];
        float o3 = (u.w - mean) * rstd * sc[c + 3] + bi[c + 3];
        o.x = (unsigned int)f2b(o0) | ((unsigned int)f2b(o1) << 16);
        o.y = (unsigned int)f2b(o2) | ((unsigned int)f2b(o3) << 16);
    }
    *(uint2*)(wy + (long)wt * 1024 + t * 4) = o;
}

// ---- transpose + cast: in fp32 (K,N) -> out bf16 (N,K) ----
__global__ void transpose_w(const float* __restrict__ in, ushort* __restrict__ out,
                            int K, int N) {
    __shared__ float tile[32][33];
    int n0 = blockIdx.x * 32, k0 = blockIdx.y * 32;
    int tx = threadIdx.x, ty = threadIdx.y;
    for (int i = 0; i < 32; i += 8)
        tile[ty + i][tx] = in[(long)(k0 + ty + i) * N + n0 + tx];
    __syncthreads();
    for (int i = 0; i < 32; i += 8)
        out[(long)(n0 + ty + i) * K + k0 + tx] = f2b(tile[tx][ty + i]);
}

// ---- legacy GEMM (m97 structure, proven) ----
template <int FLAGS, typename OT>
__global__ __launch_bounds__(256) void gemm_bt(const ushort* __restrict__ A,
                                               const ushort* __restrict__ Bt,
                                               const float* __restrict__ bias,
                                               const float* __restrict__ resid,
                                               OT* __restrict__ out,
                                               int M, int N, int K) {
    __shared__ __align__(16) ushort As[128 * 32];
    __shared__ __align__(16) ushort Bs[128 * 32];
    const int tid = threadIdx.x;
    const int lane = tid & 63, w = tid >> 6;
    const int wm = (w >> 1) * 64, wn = (w & 1) * 64;
    const int quad = lane >> 4, l16 = lane & 15;
    const int bm = blockIdx.x * 128, bn = blockIdx.y * 128;
    const int r = tid >> 2, kc = (tid & 3) * 8;
    f32x4 acc[4][4];
#pragma unroll
    for (int i = 0; i < 4; i++)
#pragma unroll
        for (int j = 0; j < 4; j++) acc[i][j] = (f32x4){0.f, 0.f, 0.f, 0.f};
    const ushort* Ag = A + (long)(bm + r) * K + kc;
    const ushort* Bg = Bt + (long)(bn + r) * K + kc;
    ushort* AsW = As + w * 512;
    ushort* BsW = Bs + w * 512;
    for (int k0 = 0; k0 < K; k0 += 32) {
        __syncthreads();
        glds16(Ag + k0, AsW);
        glds16(Ag + (long)64 * K + k0, AsW + 2048);
        glds16(Bg + k0, BsW);
        glds16(Bg + (long)64 * K + k0, BsW + 2048);
        __syncthreads();
        bf16x8 afr[4], bfr[4];
#pragma unroll
        for (int t = 0; t < 4; t++) {
            afr[t] = *(const bf16x8*)&As[(wm + t * 16 + l16) * 32 + quad * 8];
            bfr[t] = *(const bf16x8*)&Bs[(wn + t * 16 + l16) * 32 + quad * 8];
        }
#pragma unroll
        for (int tm = 0; tm < 4; tm++)
#pragma unroll
            for (int tn = 0; tn < 4; tn++)
                acc[tm][tn] = __builtin_amdgcn_mfma_f32_16x16x32_bf16(afr[tm], bfr[tn],
                                                                     acc[tm][tn], 0, 0, 0);
    }
#pragma unroll
    for (int tm = 0; tm < 4; tm++) {
#pragma unroll
        for (int j = 0; j < 4; j++) {
            int gm = bm + wm + tm * 16 + quad * 4 + j;
#pragma unroll
            for (int tn = 0; tn < 4; tn++) {
                int gn = bn + wn + tn * 16 + l16;
                float v = acc[tm][tn][j] + bias[gn];
                if (FLAGS & 1) v = 0.5f * v * (1.0f + erff(v * 0.70710678118654752f));
                if (FLAGS & 2) v += resid[(long)gm * N + gn];
                if (sizeof(OT) == 4) out[(long)gm * N + gn] = (OT)v;
                else out[(long)gm * N + gn] = (OT)f2b(v);
            }
        }
    }
}

// ======== 128x128 GEMM, 32x32x16 engine, RING-3, 48 KiB LDS, 3 blocks/CU ========
// r8 post-mortem law: per-block glds rate ~8.5 B/cyc, per-CU ~ 8.5 x blocks capped
// ~25; r8's defect was vmcnt(0) draining the SAME tile's stage (lead ~400 cyc <
// latency). Ring-3 stages tile t+2 during tile t and waits vmcnt(4) at tile end --
// the wait targets the stage issued a FULL tile earlier (r5-style invariant:
// entering tile t, all waves' stages <= t+1 are published; reads touch tile t only).
// 256 threads (4 waves of 64x64), acc[2][2] f32x16 = 64 AGPR, ~128 total regs,
// LDS 48 KB -> 3 blocks/CU (LDS-bound). Requires nt % 3 == 2 (nt = 32 or 128).
#define DSR(dst, addr, imm) \
    asm volatile("ds_read_b128 %0, %1 offset:%2" : "=&v"(dst) : "v"(addr), "n"(imm));

#define MFMA32(mf, nf, a, b) \
    acc[mf][nf] = __builtin_amdgcn_mfma_f32_32x32x16_bf16(a, b, acc[mf][nf], 0, 0, 0);

#define RDK0(c) \
    DSR(a0, a_k0, (c) * 8192 + 0)    DSR(a1, a_k0, (c) * 8192 + 2048) \
    DSR(b0, b_k0, (c) * 8192 + 0)    DSR(b1, b_k0, (c) * 8192 + 2048)
#define RDK1(c) \
    DSR(A0, a_k1, (c) * 8192 + 0)    DSR(A1, a_k1, (c) * 8192 + 2048) \
    DSR(B0, b_k1, (c) * 8192 + 0)    DSR(B1, b_k1, (c) * 8192 + 2048)

#define MFK0 \
    MFMA32(0, 0, a0, b0) MFMA32(0, 1, a0, b1) MFMA32(1, 0, a1, b0) MFMA32(1, 1, a1, b1)
#define MFK1 \
    MFMA32(0, 0, A0, B0) MFMA32(0, 1, A0, B1) MFMA32(1, 0, A1, B0) MFMA32(1, 1, A1, B1)

#define STAGE4(ts, dbuf) \
    glds16(Ag + (long)(ts) * 32, &As[dbuf][w * 512]); \
    glds16(Ag2 + (long)(ts) * 32, &As[dbuf][w * 512 + 2048]); \
    glds16(Bg + (long)(ts) * 32, &Bs[dbuf][w * 512]); \
    glds16(Bg2 + (long)(ts) * 32, &Bs[dbuf][w * 512 + 2048]);

// BODY(c = ts%3, dbuf = (ts+2)%3, ts, STG, VM): compute tile ts from slot c;
// stage tile ts+2 into slot dbuf; end with s_waitcnt VM + barrier.
#define BODY(c, dbuf, ts, STG, VM) do {                                        \
    if (STG) { STAGE4((ts) + 2, dbuf) }                                        \
    __builtin_amdgcn_sched_barrier(0);                                         \
    RDK0(c) RDK1(c)                                                            \
    asm volatile("s_waitcnt lgkmcnt(4)" ::: "memory");                         \
    __builtin_amdgcn_sched_barrier(0);                                         \
    __builtin_amdgcn_s_setprio(1); MFK0 __builtin_amdgcn_s_setprio(0);         \
    __builtin_amdgcn_sched_barrier(0);                                         \
    asm volatile("s_waitcnt lgkmcnt(0)" ::: "memory");                         \
    __builtin_amdgcn_sched_barrier(0);                                         \
    __builtin_amdgcn_s_setprio(1); MFK1 __builtin_amdgcn_s_setprio(0);         \
    __builtin_amdgcn_sched_barrier(0);                                         \
    asm volatile("s_waitcnt " VM ::: "memory");                                \
    BARX();                                                                    \
} while (0)

template <int FLAGS, typename OT>
__global__ __launch_bounds__(256, 3) void gemm128(const ushort* __restrict__ A,
                                                  const ushort* __restrict__ Bt,
                                                  const float* __restrict__ bias,
                                                  const float* __restrict__ resid,
                                                  OT* __restrict__ out,
                                                  int M, int N, int K, int nbn) {
    __shared__ __align__(64) ushort As[3][4096];   // 3 x (128 rows x 32 halfs) = 24 KB
    __shared__ __align__(64) ushort Bs[3][4096];   // 24 KB
    // bijective XCD swizzle (m204)
    const int nwg = gridDim.x;
    const int orig = blockIdx.x;
    const int q8 = nwg >> 3, r8 = nwg & 7;
    const int xcd = orig & 7, sub = orig >> 3;
    const int wgid = (xcd < r8 ? xcd * (q8 + 1) : r8 * (q8 + 1) + (xcd - r8) * q8) + sub;
    const int bm = (wgid / nbn) * 128, bn = (wgid % nbn) * 128;

    const int tid = threadIdx.x;
    const int lane = tid & 63, w = tid >> 6;          // 4 waves
    const int l31 = lane & 31, hi = lane >> 5;
    const int wm = (w >> 1) * 64, wn = (w & 1) * 64;  // 2M x 2N wave grid

    // staging: per glds a wave writes 16 rows x 64B linearly; source column slot
    // pre-swizzled with swz(r)=(r&3)^((r>>2)&1) (rule 21; lane-only expression).
    const int ly = lane >> 2;                          // 0..15
    const int c_st = (((lane & 3) ^ ((lane >> 2) & 3) ^ ((lane >> 4) & 1)) << 3);
    const ushort* Ag = A + (long)(bm + w * 16 + ly) * K + c_st;
    const ushort* Ag2 = Ag + (long)64 * K;
    const ushort* Bg = Bt + (long)(bn + w * 16 + ly) * K + c_st;
    const ushort* Bg2 = Bg + (long)64 * K;

    // read addressing (32x32x16 frags): row = base+l31, k-span hi*8 (+16 for k1);
    // physical 16B slot = logical(kh*2+hi) ^ swz(row) -- r5's verified formulas.
    const int swz = (lane & 3) ^ ((lane >> 2) & 1);
    const int s0 = swz & 1, s1 = swz >> 1;
    const int slot_k0 = (((0 ^ s1) << 1) | (hi ^ s0)) << 4;    // bytes
    const int slot_k1 = (((1 ^ s1) << 1) | (hi ^ s0)) << 4;
    const unsigned As0 =
        (unsigned)(size_t)(__attribute__((address_space(3))) ushort*)&As[0][0];
    const unsigned Bs0 =
        (unsigned)(size_t)(__attribute__((address_space(3))) ushort*)&Bs[0][0];
    const unsigned a_k0 = As0 + (unsigned)((wm + l31) * 64 + slot_k0);
    const unsigned a_k1 = As0 + (unsigned)((wm + l31) * 64 + slot_k1);
    const unsigned b_k0 = Bs0 + (unsigned)((wn + l31) * 64 + slot_k0);
    const unsigned b_k1 = Bs0 + (unsigned)((wn + l31) * 64 + slot_k1);

    f32x16 acc[2][2];
#pragma unroll
    for (int i = 0; i < 2; i++)
#pragma unroll
        for (int j = 0; j < 2; j++)
#pragma unroll
            for (int e = 0; e < 16; e++) acc[i][j][e] = 0.f;

    bf16x8 a0, a1, b0, b1;   // k0-half frags (A mf0/mf1, B nf0/nf1)
    bf16x8 A0, A1, B0, B1;   // k1-half frags

    // prologue: stage tiles 0,1 into slots 0,1; vmcnt(4) -> tile 0 landed (own
    // wave); barrier publishes it to all waves.
    STAGE4(0, 0)
    STAGE4(1, 1)
    __builtin_amdgcn_sched_barrier(0);
    asm volatile("s_waitcnt vmcnt(4)" ::: "memory");
    BARX();

    const int nt = K >> 5;  // 32 (K=1024) or 128 (K=4096); nt % 3 == 2
    for (int t = 0; t + 2 < nt; t += 3) {
        BODY(0, 2, t, 1, "vmcnt(4)");
        BODY(1, 0, t + 1, 1, "vmcnt(4)");
        BODY(2, 1, t + 2, 1, "vmcnt(4)");
    }
    // tail: tiles nt-2 (c=0) and nt-1 (c=1); no more staging.
    BODY(0, 0, 0, 0, "vmcnt(0)");   // publishes tile nt-1 (issued a full tile ago)
    // final tile nt-1 (c=1), no trailing sync
    RDK0(1) RDK1(1)
    asm volatile("s_waitcnt lgkmcnt(4)" ::: "memory");
    __builtin_amdgcn_sched_barrier(0);
    __builtin_amdgcn_s_setprio(1); MFK0 __builtin_amdgcn_s_setprio(0);
    __builtin_amdgcn_sched_barrier(0);
    asm volatile("s_waitcnt lgkmcnt(0)" ::: "memory");
    __builtin_amdgcn_sched_barrier(0);
    __builtin_amdgcn_s_setprio(1); MFK1 __builtin_amdgcn_s_setprio(0);
    __builtin_amdgcn_sched_barrier(0);

    // epilogue: C frag layout col=lane&31, row=(reg&3)+8*(reg>>2)+4*hi  [m74/m101]
#pragma unroll
    for (int mf = 0; mf < 2; mf++) {
#pragma unroll
        for (int nf = 0; nf < 2; nf++) {
            const int gn = bn + wn + nf * 32 + l31;
#pragma unroll
            for (int q = 0; q < 4; q++) {
#pragma unroll
                for (int j = 0; j < 4; j++) {
                    const int gm = bm + wm + mf * 32 + q * 8 + j + 4 * hi;
                    const long ro = (long)gm * N;
                    float v = acc[mf][nf][q * 4 + j] + bias[gn];
                    if (FLAGS & 1) v = 0.5f * v * (1.0f + erff(v * 0.70710678118654752f));
                    if (FLAGS & 2) v += resid[ro + gn];
                    if (sizeof(OT) == 4) out[ro + gn] = (OT)v;
                    else out[ro + gn] = (OT)f2b(v);
                }
            }
        }
    }
}

// ---- attention per (window, head): rel-pos via MFMA, 46 KB LDS ----
__global__ __launch_bounds__(256) void attn_kernel(const ushort* __restrict__ qkv,
                                                   ushort* __restrict__ o_out,
                                                   const float* __restrict__ relH,
                                                   const float* __restrict__ relW,
                                                   int win0, long orow0) {
    __shared__ __align__(16) ushort Vt[64 * 200];
    __shared__ __align__(16) ushort Ps[64 * 104];
    __shared__ __align__(16) ushort sc[8 * 448];
    const int head = blockIdx.y;
    const long qbase = (long)blockIdx.x * 196 * 3072 + head * 64;
    const int gwin = win0 + blockIdx.x;
    const int img = gwin / 25, wrem = gwin % 25;
    const int whh = (wrem / 5) * 14, www = (wrem % 5) * 14;
    const int tid = threadIdx.x, lane = tid & 63, w = tid >> 6;
    const int quad = lane >> 4, l16 = lane & 15;

    for (int idx = tid; idx < 196 * 64; idx += 256) {
        int k = idx >> 6, d = idx & 63;
        Vt[d * 200 + k] = qkv[qbase + 2048 + (long)k * 3072 + d];
    }
    __syncthreads();

    bf16x8 bH[2][2], bW[2][2];
#pragma unroll
    for (int nt = 0; nt < 2; nt++) {
        int n = nt * 16 + l16;
#pragma unroll
        for (int kt = 0; kt < 2; kt++) {
            bf16x8 rh = (bf16x8){0, 0, 0, 0, 0, 0, 0, 0};
            bf16x8 rw = (bf16x8){0, 0, 0, 0, 0, 0, 0, 0};
            if (n < 27) {
                const float* ph = relH + n * 64 + kt * 32 + quad * 8;
                const float* pw = relW + n * 64 + kt * 32 + quad * 8;
#pragma unroll
                for (int e = 0; e < 8; e++) {
                    rh[e] = (short)f2b(ph[e]);
                    rw[e] = (short)f2b(pw[e]);
                }
            }
            bH[nt][kt] = rh;
            bW[nt][kt] = rw;
        }
    }

    for (int tr = w; tr < 13; tr += 4) {
        int qrow = tr * 16 + l16;
        if (qrow > 195) qrow = 195;
        bf16x8 qf0 = *(const bf16x8*)(qkv + qbase + (long)qrow * 3072 + quad * 8);
        bf16x8 qf1 = *(const bf16x8*)(qkv + qbase + (long)qrow * 3072 + 32 + quad * 8);

#pragma unroll
        for (int tab = 0; tab < 2; tab++) {
#pragma unroll
            for (int nt = 0; nt < 2; nt++) {
                f32x4 a = (f32x4){0.f, 0.f, 0.f, 0.f};
                a = __builtin_amdgcn_mfma_f32_16x16x32_bf16(qf0, tab ? bW[nt][0] : bH[nt][0],
                                                            a, 0, 0, 0);
                a = __builtin_amdgcn_mfma_f32_16x16x32_bf16(qf1, tab ? bW[nt][1] : bH[nt][1],
                                                            a, 0, 0, 0);
                int col = nt * 16 + l16;
                if (col < 27) {
#pragma unroll
                    for (int j = 0; j < 4; j++)
                        sc[(w * 2 + tab) * 448 + (quad * 4 + j) * 28 + col] = f2b(a[j]);
                }
            }
        }

        f32x4 sf[13];
#pragma unroll
        for (int tc = 0; tc < 13; tc++) {
            int krow = tc * 16 + l16;
            if (krow > 195) krow = 195;
            const ushort* kp = qkv + qbase + 1024 + (long)krow * 3072 + quad * 8;
            bf16x8 kf0 = *(const bf16x8*)kp;
            bf16x8 kf1 = *(const bf16x8*)(kp + 32);
            f32x4 s = (f32x4){0.f, 0.f, 0.f, 0.f};
            s = __builtin_amdgcn_mfma_f32_16x16x32_bf16(qf0, kf0, s, 0, 0, 0);
            s = __builtin_amdgcn_mfma_f32_16x16x32_bf16(qf1, kf1, s, 0, 0, 0);
            sf[tc] = s;
        }
#pragma unroll
        for (int tc = 0; tc < 13; tc++) {
            int c = tc * 16 + l16;
            if (c < 196) {
                int kh = c / 14, kw = c - kh * 14;
#pragma unroll
                for (int j = 0; j < 4; j++) {
                    int rr = tr * 16 + quad * 4 + j;
                    if (rr > 195) rr = 195;
                    float dh = b2f(sc[(w * 2 + 0) * 448 + (quad * 4 + j) * 28 +
                                      (rr / 14 - kh + 13)]);
                    float dw = b2f(sc[(w * 2 + 1) * 448 + (quad * 4 + j) * 28 +
                                      (rr % 14 - kw + 13)]);
                    sf[tc][j] = sf[tc][j] * 0.125f + dh + dw;
                }
            } else {
#pragma unroll
                for (int j = 0; j < 4; j++) sf[tc][j] = -30000.0f;
            }
        }
        f32x4 mx = sf[0];
#pragma unroll
        for (int tc = 1; tc < 13; tc++)
#pragma unroll
            for (int j = 0; j < 4; j++) mx[j] = fmaxf(mx[j], sf[tc][j]);
        for (int off = 1; off < 16; off <<= 1)
#pragma unroll
            for (int j = 0; j < 4; j++) mx[j] = fmaxf(mx[j], __shfl_xor(mx[j], off));
        f32x4 sum = (f32x4){0.f, 0.f, 0.f, 0.f};
#pragma unroll
        for (int tc = 0; tc < 13; tc++)
#pragma unroll
            for (int j = 0; j < 4; j++) {
                float p = __expf(sf[tc][j] - mx[j]);
                sf[tc][j] = p;
                sum[j] += p;
            }
        for (int off = 1; off < 16; off <<= 1)
#pragma unroll
            for (int j = 0; j < 4; j++) sum[j] += __shfl_xor(sum[j], off);
        f32x4 linv;
#pragma unroll
        for (int j = 0; j < 4; j++) linv[j] = 1.0f / sum[j];

        f32x4 oa[4];
#pragma unroll
        for (int tn = 0; tn < 4; tn++) oa[tn] = (f32x4){0.f, 0.f, 0.f, 0.f};
#pragma unroll
        for (int tc = 0; tc < 6; tc++) {
            int c = tc * 16 + l16;
#pragma unroll
            for (int j = 0; j < 4; j++)
                Ps[(w * 16 + quad * 4 + j) * 104 + c] = f2b(sf[tc][j]);
        }
#pragma unroll
        for (int ks = 0; ks < 3; ks++) {
            bf16x8 pf = *(const bf16x8*)&Ps[(w * 16 + l16) * 104 + ks * 32 + quad * 8];
#pragma unroll
            for (int tn = 0; tn < 4; tn++) {
                bf16x8 vf = *(const bf16x8*)&Vt[(tn * 16 + l16) * 200 + ks * 32 + quad * 8];
                oa[tn] = __builtin_amdgcn_mfma_f32_16x16x32_bf16(pf, vf, oa[tn], 0, 0, 0);
            }
        }
#pragma unroll
        for (int tc = 6; tc < 13; tc++) {
            int c = tc * 16 + l16;
            if (c < 196) {
#pragma unroll
                for (int j = 0; j < 4; j++)
                    Ps[(w * 16 + quad * 4 + j) * 104 + (c - 96)] = f2b(sf[tc][j]);
            }
        }
#pragma unroll
        for (int ks = 0; ks < 3; ks++) {
            bf16x8 pf = *(const bf16x8*)&Ps[(w * 16 + l16) * 104 + ks * 32 + quad * 8];
#pragma unroll
            for (int tn = 0; tn < 4; tn++) {
                bf16x8 vf = *(const bf16x8*)&Vt[(tn * 16 + l16) * 200 + 96 + ks * 32 + quad * 8];
                oa[tn] = __builtin_amdgcn_mfma_f32_16x16x32_bf16(pf, vf, oa[tn], 0, 0, 0);
            }
        }
        for (int kk = 192; kk < 196; kk++) {
            float pj[4];
#pragma unroll
            for (int j = 0; j < 4; j++)
                pj[j] = b2f(Ps[(w * 16 + quad * 4 + j) * 104 + 96 + (kk - 192)]);
#pragma unroll
            for (int tn = 0; tn < 4; tn++) {
                float vv = b2f(Vt[(tn * 16 + l16) * 200 + kk]);
#pragma unroll
                for (int j = 0; j < 4; j++) oa[tn][j] += pj[j] * vv;
            }
        }
#pragma unroll
        for (int j = 0; j < 4; j++) {
            int rr = tr * 16 + quad * 4 + j;
            if (rr < 196) {
                int gh = whh + rr / 14, gw = www + rr % 14;
                if (gh < 64 && gw < 64) {
                    long orow = (long)img * 4096 + gh * 64 + gw - orow0;
#pragma unroll
                    for (int tn = 0; tn < 4; tn++)
                        o_out[orow * 1024 + head * 64 + tn * 16 + l16] =
                            f2b(oa[tn][j] * linv[j]);
                }
            }
        }
    }
}

// ---------------- launch ----------------
extern "C" void kernel_launch(void* const* d_in, const int* in_sizes, int n_in,
                              void* d_out, int out_size, void* d_ws, size_t ws_size,
                              hipStream_t stream) {
    const float* x = (const float*)d_in[0];
    const float* n1s = (const float*)d_in[1];
    const float* n1b = (const float*)d_in[2];
    const float* qkvW = (const float*)d_in[3];
    const float* qkvB = (const float*)d_in[4];
    const float* relH = (const float*)d_in[5];
    const float* relW = (const float*)d_in[6];
    const float* projW = (const float*)d_in[7];
    const float* projB = (const float*)d_in[8];
    const float* n2s = (const float*)d_in[9];
    const float* n2b = (const float*)d_in[10];
    const float* fc1W = (const float*)d_in[11];
    const float* fc1B = (const float*)d_in[12];
    const float* fc2W = (const float*)d_in[13];
    const float* fc2B = (const float*)d_in[14];
    float* OUT = (float*)d_out;
    char* ws = (char*)d_ws;

    if (ws_size >= 221000000ULL) {
        // ---- FULL tier (peak 220.2 MB): 11 dispatches, gemm128 ring-3 ----
        ushort* T0  = (ushort*)(ws);
        ushort* TP  = (ushort*)(ws + 6291456ULL);
        ushort* TF1 = (ushort*)(ws + 8388608ULL);
        ushort* TF2 = (ushort*)(ws + 16777216ULL);
        ushort* W0  = (ushort*)(ws + 25165824ULL);
        ushort* QKV = (ushort*)(ws + 65536000ULL);
        ushort* AO  = (ushort*)(ws + 186646528ULL);
        ushort* Z   = (ushort*)(ws + 25165824ULL);
        ushort* H   = (ushort*)(ws + 58720256ULL);

        transpose_w<<<dim3(96, 32), dim3(32, 8), 0, stream>>>(qkvW, T0, 1024, 3072);
        transpose_w<<<dim3(32, 32), dim3(32, 8), 0, stream>>>(projW, TP, 1024, 1024);
        transpose_w<<<dim3(128, 32), dim3(32, 8), 0, stream>>>(fc1W, TF1, 1024, 4096);
        transpose_w<<<dim3(32, 128), dim3(32, 8), 0, stream>>>(fc2W, TF2, 4096, 1024);
        ln_part_kernel<<<19712, 256, 0, stream>>>(x, n1s, n1b, W0, 0, 100);
        gemm128<0, ushort><<<3696, 256, 0, stream>>>(W0, T0, qkvB, nullptr, QKV,
                                                     19712, 3072, 1024, 24);
        attn_kernel<<<dim3(100, 16), 256, 0, stream>>>(QKV, AO, relH, relW, 0, 0L);
        gemm128<2, float><<<1024, 256, 0, stream>>>(AO, TP, projB, x, OUT,
                                                    16384, 1024, 1024, 8);
        ln_kernel<<<16384, 256, 0, stream>>>(OUT, n2s, n2b, Z);
        gemm128<1, ushort><<<4096, 256, 0, stream>>>(Z, TF1, fc1B, nullptr, H,
                                                     16384, 4096, 1024, 32);
        gemm128<2, float><<<1024, 256, 0, stream>>>(H, TF2, fc2B, OUT, OUT,
                                                    16384, 1024, 4096, 8);
    } else if (ws_size >= 100000000ULL) {
        // ---- MID tier (peak 99.6 MB): proven round-0 path ----
        ushort* T0  = (ushort*)(ws);
        ushort* TP  = (ushort*)(ws + 6291456ULL);
        ushort* TF1 = (ushort*)(ws + 8388608ULL);
        ushort* TF2 = (ushort*)(ws + 16777216ULL);
        ushort* AO  = (ushort*)(ws + 25165824ULL);
        ushort* W0  = (ushort*)(ws + 58720256ULL);
        ushort* QKV = (ushort*)(ws + 68943872ULL);
        ushort* Z   = (ushort*)(ws + 25165824ULL);
        ushort* H   = (ushort*)(ws + 58720256ULL);

        transpose_w<<<dim3(96, 32), dim3(32, 8), 0, stream>>>(qkvW, T0, 1024, 3072);
        transpose_w<<<dim3(32, 32), dim3(32, 8), 0, stream>>>(projW, TP, 1024, 1024);
        transpose_w<<<dim3(128, 32), dim3(32, 8), 0, stream>>>(fc1W, TF1, 1024, 4096);
        transpose_w<<<dim3(32, 128), dim3(32, 8), 0, stream>>>(fc2W, TF2, 4096, 1024);
        for (int i = 0; i < 4; i++) {
            ln_part_kernel<<<4992, 256, 0, stream>>>(x, n1s, n1b, W0, i * 25, 25);
            gemm_bt<0, ushort><<<dim3(39, 24), 256, 0, stream>>>(W0, T0, qkvB, nullptr,
                                                                 QKV, 4992, 3072, 1024);
            attn_kernel<<<dim3(25, 16), 256, 0, stream>>>(QKV, AO, relH, relW, i * 25, 0L);
        }
        gemm_bt<2, float><<<dim3(128, 8), 256, 0, stream>>>(AO, TP, projB, x, OUT,
                                                            16384, 1024, 1024);
        for (int c = 0; c < 4; c++) {
            float* xc = OUT + (long)c * 4194304;
            ln_kernel<<<4096, 256, 0, stream>>>(xc, n2s, n2b, Z);
            gemm_bt<1, ushort><<<dim3(32, 32), 256, 0, stream>>>(Z, TF1, fc1B, nullptr, H,
                                                                 4096, 4096, 1024);
            gemm_bt<2, float><<<dim3(32, 8), 256, 0, stream>>>(H, TF2, fc2B, xc, xc,
                                                               4096, 1024, 4096);
        }
    } else {
        // ---- FALLBACK (proven 31.2 MB): round-0 path ----
        ushort* T0 = (ushort*)(ws);
        ushort* W0 = (ushort*)(ws + 6291456ULL);
        ushort* W1 = (ushort*)(ws + 16515072ULL);
        ushort* W2 = (ushort*)(ws + 22806528ULL);
        ushort* F1 = (ushort*)(ws);
        ushort* F2 = (ushort*)(ws + 8388608ULL);
        ushort* Z  = (ushort*)(ws + 16777216ULL);
        ushort* H  = (ushort*)(ws + 18874368ULL);

        transpose_w<<<dim3(96, 32), dim3(32, 8), 0, stream>>>(qkvW, T0, 1024, 3072);
        for (int i = 0; i < 4; i++) {
            const float* xi = x + (long)i * 4194304;
            ln_part_kernel<<<4992, 256, 0, stream>>>(x, n1s, n1b, W0, i * 25, 25);
            for (int g = 0; g < 5; g++) {
                gemm_bt<0, ushort><<<dim3(8, 24), 256, 0, stream>>>(
                    W0 + (long)g * 980 * 1024, T0, qkvB, nullptr, W1, 1024, 3072, 1024);
                attn_kernel<<<dim3(5, 16), 256, 0, stream>>>(W1, W2, relH, relW,
                                                             i * 25 + g * 5, (long)i * 4096);
            }
            transpose_w<<<dim3(32, 32), dim3(32, 8), 0, stream>>>(projW, W1, 1024, 1024);
            gemm_bt<2, float><<<dim3(32, 8), 256, 0, stream>>>(
                W2, W1, projB, xi, OUT + (long)i * 4194304, 4096, 1024, 1024);
        }
        transpose_w<<<dim3(128, 32), dim3(32, 8), 0, stream>>>(fc1W, F1, 1024, 4096);
        transpose_w<<<dim3(32, 128), dim3(32, 8), 0, stream>>>(fc2W, F2, 4096, 1024);
        for (int c = 0; c < 16; c++) {
            float* xc = OUT + (long)c * 1048576;
            ln_kernel<<<1024, 256, 0, stream>>>(xc, n2s, n2b, Z);
            gemm_bt<1, ushort><<<dim3(8, 32), 256, 0, stream>>>(Z, F1, fc1B, nullptr, H,
                                                                1024, 4096, 1024);
            gemm_bt<2, float><<<dim3(8, 8), 256, 0, stream>>>(H, F2, fc2B, xc, xc,
                                                              1024, 1024, 4096);
        }
    }
}